// Round 3
// baseline (498.530 us; speedup 1.0000x reference)
//
#include <hip/hip_runtime.h>

typedef _Float16 f16;
typedef _Float16 half8 __attribute__((ext_vector_type(8)));
typedef _Float16 half4_t __attribute__((ext_vector_type(4)));
typedef float f32x4 __attribute__((ext_vector_type(4)));

#define T_SEQ 2048
#define B_SZ 2
#define DM 2048
#define NH 16
#define NKV 4
#define DH 128
#define NQKV 2560    // (16+4)*128
#define NALL 4736    // 2560 (qkv) + 128 (rk pad) + 2048 (gate)
#define COL_RK 2560
#define COL_G 2688
#define M_ROWS 4096  // B*T
#define WIN 1024

typedef __attribute__((address_space(1))) const unsigned int guint;
typedef __attribute__((address_space(3))) unsigned int luint;
__device__ __forceinline__ void gload16(const void* g, void* l) {
  __builtin_amdgcn_global_load_lds((guint*)g, (luint*)l, 16, 0, 0);
}

// ---------------- fp32 -> f16 elementwise ----------------
__global__ void k_cvt(const float* __restrict__ in, f16* __restrict__ out, int n) {
  int i = (blockIdx.x * 256 + threadIdx.x) * 4;
  if (i >= n) return;
  float4 v = *(const float4*)(in + i);
  half4_t o;
  o[0] = (f16)v.x; o[1] = (f16)v.y; o[2] = (f16)v.z; o[3] = (f16)v.w;
  *(half4_t*)(out + i) = o;
}

// ---------------- fp32 (K,N) -> f16 (N,K) transpose-convert ----------------
__global__ __launch_bounds__(256) void k_cvt_t(const float* __restrict__ W,
                                               f16* __restrict__ Wt, int K, int N) {
  __shared__ float tile[32][33];
  int k0 = blockIdx.x * 32, n0 = blockIdx.y * 32;
  int tx = threadIdx.x & 31, ty = threadIdx.x >> 5; // 32 x 8
#pragma unroll
  for (int r = 0; r < 32; r += 8)
    tile[ty + r][tx] = W[(size_t)(k0 + ty + r) * N + n0 + tx];
  __syncthreads();
#pragma unroll
  for (int r = 0; r < 32; r += 8)
    Wt[(size_t)(n0 + ty + r) * K + k0 + tx] = (f16)tile[tx][ty + r];
}

// ---------------- f16 [T][128] -> f16 [128][T] per matrix ----------------
__global__ __launch_bounds__(256) void k_vt(const f16* __restrict__ v, f16* __restrict__ vt) {
  __shared__ f16 tile[32][34];
  int t0 = blockIdx.x * 32, d0 = blockIdx.y * 32, m = blockIdx.z;
  int tx = threadIdx.x & 31, ty = threadIdx.x >> 5;
  const f16* src = v + (size_t)m * T_SEQ * DH;
  f16* dst = vt + (size_t)m * T_SEQ * DH;
#pragma unroll
  for (int r = 0; r < 32; r += 8)
    tile[ty + r][tx] = src[(size_t)(t0 + ty + r) * DH + d0 + tx];
  __syncthreads();
#pragma unroll
  for (int r = 0; r < 32; r += 8)
    dst[(size_t)(d0 + ty + r) * T_SEQ + t0 + tx] = tile[tx][ty + r];
}

// ------- C[M,NALL](f16) = A[M,K](f16) * Bt[NALL,K]^T, m97 structure + XCD swizzle -------
__global__ __launch_bounds__(256) void k_gemm_lds(const f16* __restrict__ A,
                                                  const f16* __restrict__ Bt,
                                                  f16* __restrict__ C,
                                                  int N, int K) {
  __shared__ __align__(16) f16 As[128 * 32];
  __shared__ __align__(16) f16 Bs[128 * 32];
  // bijective XCD swizzle: nwg = 37*32 = 1184 = 8*148
  unsigned orig = blockIdx.y * 37u + blockIdx.x;
  unsigned swz = (orig & 7u) * 148u + (orig >> 3);
  int m0 = (int)(swz / 37u) * 128;
  int n0 = (int)(swz % 37u) * 128;
  int tid = threadIdx.x, lane = tid & 63, w = tid >> 6;
  int wm = (w >> 1) * 64, wn = (w & 1) * 64;
  int fr = lane & 15, fq = lane >> 4;
  f32x4 acc[4][4] = {};
  int r0 = tid >> 2;          // staging row (0..63)
  int c0 = (tid & 3) * 8;     // staging col in halves
  const f16* Ag0 = A + (size_t)(m0 + r0) * K + c0;
  const f16* Ag1 = A + (size_t)(m0 + 64 + r0) * K + c0;
  const f16* Bg0 = Bt + (size_t)(n0 + r0) * K + c0;
  const f16* Bg1 = Bt + (size_t)(n0 + 64 + r0) * K + c0;
  char* Asb = (char*)As;
  char* Bsb = (char*)Bs;
  for (int k0 = 0; k0 < K; k0 += 32) {
    gload16(Ag0 + k0, Asb + w * 1024);
    gload16(Ag1 + k0, Asb + 4096 + w * 1024);
    gload16(Bg0 + k0, Bsb + w * 1024);
    gload16(Bg1 + k0, Bsb + 4096 + w * 1024);
    __syncthreads();
    half8 af[4], bf[4];
#pragma unroll
    for (int i = 0; i < 4; ++i)
      af[i] = *(const half8*)(Asb + (wm + i * 16 + fr) * 64 + fq * 16);
#pragma unroll
    for (int j = 0; j < 4; ++j)
      bf[j] = *(const half8*)(Bsb + (wn + j * 16 + fr) * 64 + fq * 16);
#pragma unroll
    for (int i = 0; i < 4; ++i)
#pragma unroll
      for (int j = 0; j < 4; ++j)
        acc[i][j] = __builtin_amdgcn_mfma_f32_16x16x32_f16(af[i], bf[j], acc[i][j], 0, 0, 0);
    __syncthreads();
  }
#pragma unroll
  for (int i = 0; i < 4; ++i) {
    int row = m0 + wm + i * 16 + fq * 4;
#pragma unroll
    for (int j = 0; j < 4; ++j) {
      int col = n0 + wn + j * 16 + fr;
      f16* Cp = C + (size_t)row * N + col;
#pragma unroll
      for (int rr = 0; rr < 4; ++rr) Cp[(size_t)rr * N] = (f16)acc[i][j][rr];
    }
  }
}

// ---------------- RMSNorm + RoPE + scale + pack q/k/v as f16 ----------------
__global__ __launch_bounds__(256) void k_postproc(
    const f16* __restrict__ CA,
    const float* __restrict__ brk, const float* __restrict__ sscal,
    f16* __restrict__ q16, f16* __restrict__ k16, f16* __restrict__ v16) {
  int row = blockIdx.x;              // b*T + t
  int b = row >> 11, t = row & 2047;
  int lane = threadIdx.x & 63, wid = threadIdx.x >> 6;
  int ridx = lane & 31;
  float inv_freq = powf(10000.0f, -(float)(2 * ridx) / 64.0f);
  float fr = (float)t * inv_freq;
  float cs = cosf(fr), sn = sinf(fr);
  float logpos = logf(fminf((float)(t + 1), 1024.0f));
  // 1/sqrt(128) * log2(e): attention works in exp2 domain
  const float rsqrt_d_log2e = 0.08838834764831845f * 1.4426950408889634f;
  const f16* Crow = CA + (size_t)row * NALL;
#pragma unroll
  for (int p = 0; p < 5; ++p) {
    int h = p * 4 + wid; // 0..19
    float v0 = (float)Crow[h * 128 + lane];
    float v1 = (float)Crow[h * 128 + 64 + lane];
    float ss = v0 * v0 + v1 * v1;
#pragma unroll
    for (int m = 1; m < 64; m <<= 1) ss += __shfl_xor(ss, m);
    float rms = rsqrtf(ss * (1.0f / 128.0f) + 1e-6f);
    v0 *= rms; v1 *= rms;
    if (h < NH) {
      float part = __shfl_xor(v1, 32);
      float vr = (lane < 32) ? (v1 * cs + part * sn) : (v1 * cs - part * sn);
      float scale = sscal[h] * logpos * rsqrt_d_log2e;
      size_t qb = ((size_t)(b * NH + h) * T_SEQ + t) * DH;
      q16[qb + lane]      = (f16)(v0 * scale);
      q16[qb + 64 + lane] = (f16)(vr * scale);
    } else {
      int hk = h - NH;
      size_t kb = ((size_t)(b * NKV + hk) * T_SEQ + t) * DH;
      k16[kb + lane]      = (f16)v0;  // tied kv
      v16[kb + lane]      = (f16)v0;  // tied kv
      v16[kb + 64 + lane] = (f16)v1;  // v
    }
  }
  if (wid == 0) {
    float kr = (float)Crow[COL_RK + lane] + brk[lane];
    float part = __shfl_xor(kr, 32);
    float vr = (lane < 32) ? (kr * cs + part * sn) : (kr * cs - part * sn);
    f16 hv = (f16)vr;
#pragma unroll
    for (int hk = 0; hk < NKV; ++hk)
      k16[((size_t)(b * NKV + hk) * T_SEQ + t) * DH + 64 + lane] = hv;
  }
}

// ---------------- sliding-window flash attention + silu(g) epilogue ----------------
// BQ=128 (8 waves x 16 q-rows), KV tile 64.
// K tile: [64][128] f16, 256B rows, 16 slots of 16B, slot ^= (row&7)
// V^T tile: [128][64] f16, 128B rows, 8 slots,  slot ^= (row&7)
// P tile (per wave): [16][64] f16, 128B rows, 8 slots, slot ^= (row&7)
__global__ __launch_bounds__(512, 6) void k_attn(
    const f16* __restrict__ q16, const f16* __restrict__ k16, const f16* __restrict__ vt16,
    const f16* __restrict__ gA, float* __restrict__ out) {
  __shared__ __align__(16) f16 Ks[64 * DH];
  __shared__ __align__(16) f16 Vs[DH * 64];
  __shared__ __align__(16) f16 Ps[8 * 16 * 64];
  int bx = blockIdx.x;
  int qt = (bx & 1) ? (15 - (bx >> 1)) : (bx >> 1);  // load-balance heavy/light tiles
  int h = blockIdx.y, b = blockIdx.z, hk = h >> 2;
  int tid = threadIdx.x, lane = tid & 63, w = tid >> 6;
  int i0 = qt * 128, iw = i0 + w * 16;
  int fr = lane & 15, fq = lane >> 4;

  char* Ksb = (char*)Ks;
  char* Vsb = (char*)Vs;
  char* Psb = (char*)Ps + w * 2048;

  const f16* qbase = q16 + ((size_t)(b * NH + h) * T_SEQ + iw + fr) * DH;
  half8 qf[4];
#pragma unroll
  for (int kb = 0; kb < 4; ++kb) qf[kb] = *(const half8*)&qbase[kb * 32 + fq * 8];

  f32x4 o[8] = {};
  float mrow[4] = {-1e30f, -1e30f, -1e30f, -1e30f};
  float lrow[4] = {0.f, 0.f, 0.f, 0.f};

  const f16* kg = k16 + (size_t)(b * NKV + hk) * T_SEQ * DH;   // [T][128]
  const f16* vg = vt16 + (size_t)(b * NKV + hk) * T_SEQ * DH;  // [128][T]

  int jtTop = qt * 2 + 1;
  int jt0 = qt >= 8 ? qt * 2 - 16 : 0;
  for (int jt = jt0; jt <= jtTop; ++jt) {
    int j0 = jt * 64;
    // ---- stage K (16KB) + V^T (16KB), inverse-swizzled source, linear LDS dest ----
#pragma unroll
    for (int i = 0; i < 2; ++i) {
      int r = i * 32 + (tid >> 4);
      int c = (tid & 15) ^ (r & 7);
      gload16(kg + (size_t)(j0 + r) * DH + c * 8, Ksb + i * 8192 + w * 1024);
    }
#pragma unroll
    for (int i = 0; i < 2; ++i) {
      int r = i * 64 + (tid >> 3);
      int c = (tid & 7) ^ (r & 7);
      gload16(vg + (size_t)r * T_SEQ + j0 + c * 8, Vsb + i * 8192 + w * 1024);
    }
    __syncthreads();   // drains vmcnt(0): tiles resident

    // full-masked wave skip on boundary tiles
    bool active = (jt == jtTop) ? (w >= 4)
                : ((qt >= 8 && jt == jt0) ? (w < 4) : true);
    if (active) {
      // ---- S = Q K^T (16 q-rows x 64 keys per wave) ----
      f32x4 s[4] = {};
      __builtin_amdgcn_s_setprio(1);
#pragma unroll
      for (int nf = 0; nf < 4; ++nf) {
        int row = nf * 16 + fr;
        int sw = fr & 7;
#pragma unroll
        for (int kb = 0; kb < 4; ++kb) {
          half8 bfv = *(const half8*)(Ksb + row * 256 + ((((kb << 2) | fq) ^ sw) << 4));
          s[nf] = __builtin_amdgcn_mfma_f32_16x16x32_f16(qf[kb], bfv, s[nf], 0, 0, 0);
        }
      }
      __builtin_amdgcn_s_setprio(0);
      // ---- masking ----
      int il = (w << 4) + (fq << 2);
      if (jt >= (qt << 1)) {            // causal tiles (last two)
        int dc = (jt << 6) - i0;
#pragma unroll
        for (int nf = 0; nf < 4; ++nf) {
          int jo = nf * 16 + fr + dc;
#pragma unroll
          for (int r = 0; r < 4; ++r)
            if (jo > il + r) s[nf][r] = -3e38f;
        }
      } else if (qt >= 8 && jt - jt0 < 2) {  // window-edge tiles (first two)
        int dl = (jt - jt0) << 6;
#pragma unroll
        for (int nf = 0; nf < 4; ++nf) {
          int jo = nf * 16 + fr + dl;
#pragma unroll
          for (int r = 0; r < 4; ++r)
            if (jo < il + r) s[nf][r] = -3e38f;
        }
      }
      // ---- online softmax (exp2 domain), defer-max rescale ----
      float tm[4];
#pragma unroll
      for (int r = 0; r < 4; ++r)
        tm[r] = fmaxf(fmaxf(s[0][r], s[1][r]), fmaxf(s[2][r], s[3][r]));
#pragma unroll
      for (int r = 0; r < 4; ++r) {
        tm[r] = fmaxf(tm[r], __shfl_xor(tm[r], 1));
        tm[r] = fmaxf(tm[r], __shfl_xor(tm[r], 2));
        tm[r] = fmaxf(tm[r], __shfl_xor(tm[r], 4));
        tm[r] = fmaxf(tm[r], __shfl_xor(tm[r], 8));
      }
      bool need = false;
#pragma unroll
      for (int r = 0; r < 4; ++r) need = need || (tm[r] > mrow[r] + 8.0f);
      if (__any(need)) {
#pragma unroll
        for (int r = 0; r < 4; ++r) {
          float mn = fmaxf(mrow[r], tm[r]);
          float sc = exp2f(mrow[r] - mn);
          mrow[r] = mn;
          lrow[r] *= sc;
#pragma unroll
          for (int of = 0; of < 8; ++of) o[of][r] *= sc;
        }
      }
      float ls[4] = {0.f, 0.f, 0.f, 0.f};
#pragma unroll
      for (int nf = 0; nf < 4; ++nf)
#pragma unroll
        for (int r = 0; r < 4; ++r) {
          float pv = exp2f(s[nf][r] - mrow[r]);
          s[nf][r] = pv;
          ls[r] += pv;
        }
#pragma unroll
      for (int r = 0; r < 4; ++r) {
        float t2 = ls[r];
        t2 += __shfl_xor(t2, 1); t2 += __shfl_xor(t2, 2);
        t2 += __shfl_xor(t2, 4); t2 += __shfl_xor(t2, 8);
        lrow[r] += t2;
      }
      // ---- P -> per-wave LDS (swizzled), wave-local ordering only ----
#pragma unroll
      for (int nf = 0; nf < 4; ++nf) {
        int sbase = (nf << 1) + (fr >> 3);
        int boff = (fr & 7) << 1;
#pragma unroll
        for (int r = 0; r < 4; ++r) {
          int q = (fq << 2) + r;
          *(f16*)(Psb + q * 128 + ((sbase ^ (q & 7)) << 4) + boff) = (f16)s[nf][r];
        }
      }
      asm volatile("s_waitcnt lgkmcnt(0)" ::: "memory");
      __builtin_amdgcn_sched_barrier(0);
      half8 pf0 = *(const half8*)(Psb + fr * 128 + (((fq) ^ (fr & 7)) << 4));
      half8 pf1 = *(const half8*)(Psb + fr * 128 + (((4 | fq) ^ (fr & 7)) << 4));
      // ---- O += P V ----
      __builtin_amdgcn_s_setprio(1);
#pragma unroll
      for (int of = 0; of < 8; ++of) {
        int vrow0 = of * 16 + fr;
        int sw = fr & 7;
        half8 v0 = *(const half8*)(Vsb + vrow0 * 128 + ((fq ^ sw) << 4));
        half8 v1 = *(const half8*)(Vsb + vrow0 * 128 + (((4 | fq) ^ sw) << 4));
        o[of] = __builtin_amdgcn_mfma_f32_16x16x32_f16(pf0, v0, o[of], 0, 0, 0);
        o[of] = __builtin_amdgcn_mfma_f32_16x16x32_f16(pf1, v1, o[of], 0, 0, 0);
      }
      __builtin_amdgcn_s_setprio(0);
    }
    __syncthreads();   // all waves done reading Ks/Vs before next stage
  }
  // ---- epilogue: normalize + silu(g), write (B,T,H,D) ----
  const f16* gb = gA + ((size_t)(b * T_SEQ) + iw) * NALL + COL_G + h * DH;
  float* ob = out + ((size_t)(b * T_SEQ) + iw) * DM + h * DH;
#pragma unroll
  for (int r = 0; r < 4; ++r) {
    float inv = 1.0f / lrow[r];
    int ir = fq * 4 + r;
#pragma unroll
    for (int of = 0; of < 8; ++of) {
      int d = of * 16 + fr;
      float gv = (float)gb[(size_t)ir * NALL + d];
      float sig = gv / (1.0f + expf(-gv));
      ob[(size_t)ir * DM + d] = o[of][r] * inv * sig;
    }
  }
}

extern "C" void kernel_launch(void* const* d_in, const int* in_sizes, int n_in,
                              void* d_out, int out_size, void* d_ws, size_t ws_size,
                              hipStream_t stream) {
  const float* x     = (const float*)d_in[0];
  const float* Wqkv  = (const float*)d_in[1];
  const float* Wrk   = (const float*)d_in[2];
  const float* brk   = (const float*)d_in[3];
  const float* sscal = (const float*)d_in[4];
  const float* Wg    = (const float*)d_in[5];
  float* out = (float*)d_out;
  char* ws = (char*)d_ws;
  size_t off = 0;
  auto alloc = [&](size_t bytes) -> void* {
    void* p = ws + off;
    off += (bytes + 255) & ~(size_t)255;
    return p;
  };
  f16* x16     = (f16*)alloc((size_t)M_ROWS * DM * 2);
  f16* BtAll   = (f16*)alloc((size_t)NALL * DM * 2);
  f16* CAll    = (f16*)alloc((size_t)M_ROWS * NALL * 2);
  f16* q16     = (f16*)alloc((size_t)B_SZ * NH * T_SEQ * DH * 2);
  f16* k16     = (f16*)alloc((size_t)B_SZ * NKV * T_SEQ * DH * 2);
  f16* v16     = (f16*)alloc((size_t)B_SZ * NKV * T_SEQ * DH * 2);
  f16* vt16    = (f16*)alloc((size_t)B_SZ * NKV * T_SEQ * DH * 2);

  k_cvt<<<(M_ROWS * DM / 4 + 255) / 256, 256, 0, stream>>>(x, x16, M_ROWS * DM);
  k_cvt_t<<<dim3(DM / 32, NQKV / 32), 256, 0, stream>>>(Wqkv, BtAll, DM, NQKV);
  k_cvt_t<<<dim3(DM / 32, 64 / 32), 256, 0, stream>>>(Wrk, BtAll + (size_t)COL_RK * DM, DM, 64);
  k_cvt_t<<<dim3(DM / 32, DM / 32), 256, 0, stream>>>(Wg, BtAll + (size_t)COL_G * DM, DM, DM);

  k_gemm_lds<<<dim3(NALL / 128, M_ROWS / 128), 256, 0, stream>>>(x16, BtAll, CAll, NALL, DM);

  k_postproc<<<M_ROWS, 256, 0, stream>>>(CAll, brk, sscal, q16, k16, v16);
  k_vt<<<dim3(T_SEQ / 32, DH / 32, B_SZ * NKV), 256, 0, stream>>>(v16, vt16);

  k_attn<<<dim3(T_SEQ / 128, NH, B_SZ), 512, 0, stream>>>(q16, k16, vt16, CAll, out);
}

// Round 4
// 367.222 us; speedup vs baseline: 1.3576x; 1.3576x over previous
//
#include <hip/hip_runtime.h>

typedef _Float16 f16;
typedef _Float16 half8 __attribute__((ext_vector_type(8)));
typedef _Float16 half4_t __attribute__((ext_vector_type(4)));
typedef float f32x4 __attribute__((ext_vector_type(4)));

#define T_SEQ 2048
#define B_SZ 2
#define DM 2048
#define NH 16
#define NKV 4
#define DH 128
#define NQKV 2560    // (16+4)*128
#define NALL 4736    // 2560 (qkv) + 128 (rk pad) + 2048 (gate)
#define COL_RK 2560
#define COL_G 2688
#define M_ROWS 4096  // B*T
#define WIN 1024

typedef __attribute__((address_space(1))) const unsigned int guint;
typedef __attribute__((address_space(3))) unsigned int luint;
__device__ __forceinline__ void gload16(const void* g, void* l) {
  __builtin_amdgcn_global_load_lds((guint*)g, (luint*)l, 16, 0, 0);
}

// ---------------- fp32 -> f16 elementwise ----------------
__global__ void k_cvt(const float* __restrict__ in, f16* __restrict__ out, int n) {
  int i = (blockIdx.x * 256 + threadIdx.x) * 4;
  if (i >= n) return;
  float4 v = *(const float4*)(in + i);
  half4_t o;
  o[0] = (f16)v.x; o[1] = (f16)v.y; o[2] = (f16)v.z; o[3] = (f16)v.w;
  *(half4_t*)(out + i) = o;
}

// ---------------- fp32 (K,N) -> f16 (N,K) transpose-convert ----------------
__global__ __launch_bounds__(256) void k_cvt_t(const float* __restrict__ W,
                                               f16* __restrict__ Wt, int K, int N) {
  __shared__ float tile[32][33];
  int k0 = blockIdx.x * 32, n0 = blockIdx.y * 32;
  int tx = threadIdx.x & 31, ty = threadIdx.x >> 5; // 32 x 8
#pragma unroll
  for (int r = 0; r < 32; r += 8)
    tile[ty + r][tx] = W[(size_t)(k0 + ty + r) * N + n0 + tx];
  __syncthreads();
#pragma unroll
  for (int r = 0; r < 32; r += 8)
    Wt[(size_t)(n0 + ty + r) * K + k0 + tx] = (f16)tile[tx][ty + r];
}

// ---------------- f16 [T][128] -> f16 [128][T] per matrix ----------------
__global__ __launch_bounds__(256) void k_vt(const f16* __restrict__ v, f16* __restrict__ vt) {
  __shared__ f16 tile[32][34];
  int t0 = blockIdx.x * 32, d0 = blockIdx.y * 32, m = blockIdx.z;
  int tx = threadIdx.x & 31, ty = threadIdx.x >> 5;
  const f16* src = v + (size_t)m * T_SEQ * DH;
  f16* dst = vt + (size_t)m * T_SEQ * DH;
#pragma unroll
  for (int r = 0; r < 32; r += 8)
    tile[ty + r][tx] = src[(size_t)(t0 + ty + r) * DH + d0 + tx];
  __syncthreads();
#pragma unroll
  for (int r = 0; r < 32; r += 8)
    dst[(size_t)(d0 + ty + r) * T_SEQ + t0 + tx] = tile[tx][ty + r];
}

// ------- C[M,NALL](f16) = A[M,K](f16) * Bt[NALL,K]^T, m97 structure + XCD swizzle -------
__global__ __launch_bounds__(256) void k_gemm_lds(const f16* __restrict__ A,
                                                  const f16* __restrict__ Bt,
                                                  f16* __restrict__ C,
                                                  int N, int K) {
  __shared__ __align__(16) f16 As[128 * 32];
  __shared__ __align__(16) f16 Bs[128 * 32];
  // bijective XCD swizzle: nwg = 37*32 = 1184 = 8*148
  unsigned orig = blockIdx.y * 37u + blockIdx.x;
  unsigned swz = (orig & 7u) * 148u + (orig >> 3);
  int m0 = (int)(swz / 37u) * 128;
  int n0 = (int)(swz % 37u) * 128;
  int tid = threadIdx.x, lane = tid & 63, w = tid >> 6;
  int wm = (w >> 1) * 64, wn = (w & 1) * 64;
  int fr = lane & 15, fq = lane >> 4;
  f32x4 acc[4][4] = {};
  int r0 = tid >> 2;          // staging row (0..63)
  int c0 = (tid & 3) * 8;     // staging col in halves
  const f16* Ag0 = A + (size_t)(m0 + r0) * K + c0;
  const f16* Ag1 = A + (size_t)(m0 + 64 + r0) * K + c0;
  const f16* Bg0 = Bt + (size_t)(n0 + r0) * K + c0;
  const f16* Bg1 = Bt + (size_t)(n0 + 64 + r0) * K + c0;
  char* Asb = (char*)As;
  char* Bsb = (char*)Bs;
  for (int k0 = 0; k0 < K; k0 += 32) {
    gload16(Ag0 + k0, Asb + w * 1024);
    gload16(Ag1 + k0, Asb + 4096 + w * 1024);
    gload16(Bg0 + k0, Bsb + w * 1024);
    gload16(Bg1 + k0, Bsb + 4096 + w * 1024);
    __syncthreads();
    half8 af[4], bf[4];
#pragma unroll
    for (int i = 0; i < 4; ++i)
      af[i] = *(const half8*)(Asb + (wm + i * 16 + fr) * 64 + fq * 16);
#pragma unroll
    for (int j = 0; j < 4; ++j)
      bf[j] = *(const half8*)(Bsb + (wn + j * 16 + fr) * 64 + fq * 16);
#pragma unroll
    for (int i = 0; i < 4; ++i)
#pragma unroll
      for (int j = 0; j < 4; ++j)
        acc[i][j] = __builtin_amdgcn_mfma_f32_16x16x32_f16(af[i], bf[j], acc[i][j], 0, 0, 0);
    __syncthreads();
  }
#pragma unroll
  for (int i = 0; i < 4; ++i) {
    int row = m0 + wm + i * 16 + fq * 4;
#pragma unroll
    for (int j = 0; j < 4; ++j) {
      int col = n0 + wn + j * 16 + fr;
      f16* Cp = C + (size_t)row * N + col;
#pragma unroll
      for (int rr = 0; rr < 4; ++rr) Cp[(size_t)rr * N] = (f16)acc[i][j][rr];
    }
  }
}

// ---------------- RMSNorm + RoPE + scale + pack q/k/v as f16 ----------------
__global__ __launch_bounds__(256) void k_postproc(
    const f16* __restrict__ CA,
    const float* __restrict__ brk, const float* __restrict__ sscal,
    f16* __restrict__ q16, f16* __restrict__ k16, f16* __restrict__ v16) {
  int row = blockIdx.x;              // b*T + t
  int b = row >> 11, t = row & 2047;
  int lane = threadIdx.x & 63, wid = threadIdx.x >> 6;
  int ridx = lane & 31;
  float inv_freq = powf(10000.0f, -(float)(2 * ridx) / 64.0f);
  float fr = (float)t * inv_freq;
  float cs = cosf(fr), sn = sinf(fr);
  float logpos = logf(fminf((float)(t + 1), 1024.0f));
  // 1/sqrt(128) * log2(e): attention works in exp2 domain
  const float rsqrt_d_log2e = 0.08838834764831845f * 1.4426950408889634f;
  const f16* Crow = CA + (size_t)row * NALL;
#pragma unroll
  for (int p = 0; p < 5; ++p) {
    int h = p * 4 + wid; // 0..19
    float v0 = (float)Crow[h * 128 + lane];
    float v1 = (float)Crow[h * 128 + 64 + lane];
    float ss = v0 * v0 + v1 * v1;
#pragma unroll
    for (int m = 1; m < 64; m <<= 1) ss += __shfl_xor(ss, m);
    float rms = rsqrtf(ss * (1.0f / 128.0f) + 1e-6f);
    v0 *= rms; v1 *= rms;
    if (h < NH) {
      float part = __shfl_xor(v1, 32);
      float vr = (lane < 32) ? (v1 * cs + part * sn) : (v1 * cs - part * sn);
      float scale = sscal[h] * logpos * rsqrt_d_log2e;
      size_t qb = ((size_t)(b * NH + h) * T_SEQ + t) * DH;
      q16[qb + lane]      = (f16)(v0 * scale);
      q16[qb + 64 + lane] = (f16)(vr * scale);
    } else {
      int hk = h - NH;
      size_t kb = ((size_t)(b * NKV + hk) * T_SEQ + t) * DH;
      k16[kb + lane]      = (f16)v0;  // tied kv
      v16[kb + lane]      = (f16)v0;  // tied kv
      v16[kb + 64 + lane] = (f16)v1;  // v
    }
  }
  if (wid == 0) {
    float kr = (float)Crow[COL_RK + lane] + brk[lane];
    float part = __shfl_xor(kr, 32);
    float vr = (lane < 32) ? (kr * cs + part * sn) : (kr * cs - part * sn);
    f16 hv = (f16)vr;
#pragma unroll
    for (int hk = 0; hk < NKV; ++hk)
      k16[((size_t)(b * NKV + hk) * T_SEQ + t) * DH + 64 + lane] = hv;
  }
}

// ---------------- sliding-window flash attention + silu(g) epilogue ----------------
// BQ=128 (8 waves x 16 q-rows), KV tile 64.
// K tile: [64][128] f16, 256B rows, 16 slots of 16B, slot ^= (row&7)
// V^T tile: [128][64] f16, 128B rows, 8 slots,  slot ^= (row&7)
// P tile (per wave): [16][64] f16, 128B rows, 8 slots, slot ^= (row&7)
// NOTE: launch_bounds min-waves MUST stay low — (512,6) capped VGPRs at 40 and
// spilled the o[] accumulator to scratch (440MB fetch, 2.3x slowdown, round 3).
__global__ __launch_bounds__(512, 2) void k_attn(
    const f16* __restrict__ q16, const f16* __restrict__ k16, const f16* __restrict__ vt16,
    const f16* __restrict__ gA, float* __restrict__ out) {
  __shared__ __align__(16) f16 Ks[64 * DH];
  __shared__ __align__(16) f16 Vs[DH * 64];
  __shared__ __align__(16) f16 Ps[8 * 16 * 64];
  int bx = blockIdx.x;
  int qt = (bx & 1) ? (15 - (bx >> 1)) : (bx >> 1);  // load-balance heavy/light tiles
  int h = blockIdx.y, b = blockIdx.z, hk = h >> 2;
  int tid = threadIdx.x, lane = tid & 63, w = tid >> 6;
  int i0 = qt * 128, iw = i0 + w * 16;
  int fr = lane & 15, fq = lane >> 4;

  char* Ksb = (char*)Ks;
  char* Vsb = (char*)Vs;
  char* Psb = (char*)Ps + w * 2048;

  const f16* qbase = q16 + ((size_t)(b * NH + h) * T_SEQ + iw + fr) * DH;
  half8 qf[4];
#pragma unroll
  for (int kb = 0; kb < 4; ++kb) qf[kb] = *(const half8*)&qbase[kb * 32 + fq * 8];

  f32x4 o[8] = {};
  float mrow[4] = {-1e30f, -1e30f, -1e30f, -1e30f};
  float lrow[4] = {0.f, 0.f, 0.f, 0.f};

  const f16* kg = k16 + (size_t)(b * NKV + hk) * T_SEQ * DH;   // [T][128]
  const f16* vg = vt16 + (size_t)(b * NKV + hk) * T_SEQ * DH;  // [128][T]

  int jtTop = qt * 2 + 1;
  int jt0 = qt >= 8 ? qt * 2 - 16 : 0;
  for (int jt = jt0; jt <= jtTop; ++jt) {
    int j0 = jt * 64;
    // ---- stage K (16KB) + V^T (16KB), inverse-swizzled source, linear LDS dest ----
#pragma unroll
    for (int i = 0; i < 2; ++i) {
      int r = i * 32 + (tid >> 4);
      int c = (tid & 15) ^ (r & 7);
      gload16(kg + (size_t)(j0 + r) * DH + c * 8, Ksb + i * 8192 + w * 1024);
    }
#pragma unroll
    for (int i = 0; i < 2; ++i) {
      int r = i * 64 + (tid >> 3);
      int c = (tid & 7) ^ (r & 7);
      gload16(vg + (size_t)r * T_SEQ + j0 + c * 8, Vsb + i * 8192 + w * 1024);
    }
    __syncthreads();   // drains vmcnt(0): tiles resident

    // full-masked wave skip on boundary tiles
    bool active = (jt == jtTop) ? (w >= 4)
                : ((qt >= 8 && jt == jt0) ? (w < 4) : true);
    if (active) {
      // ---- S = Q K^T (16 q-rows x 64 keys per wave) ----
      f32x4 s[4] = {};
      __builtin_amdgcn_s_setprio(1);
#pragma unroll
      for (int nf = 0; nf < 4; ++nf) {
        int row = nf * 16 + fr;
        int sw = fr & 7;
#pragma unroll
        for (int kb = 0; kb < 4; ++kb) {
          half8 bfv = *(const half8*)(Ksb + row * 256 + ((((kb << 2) | fq) ^ sw) << 4));
          s[nf] = __builtin_amdgcn_mfma_f32_16x16x32_f16(qf[kb], bfv, s[nf], 0, 0, 0);
        }
      }
      __builtin_amdgcn_s_setprio(0);
      // ---- masking ----
      int il = (w << 4) + (fq << 2);
      if (jt >= (qt << 1)) {            // causal tiles (last two)
        int dc = (jt << 6) - i0;
#pragma unroll
        for (int nf = 0; nf < 4; ++nf) {
          int jo = nf * 16 + fr + dc;
#pragma unroll
          for (int r = 0; r < 4; ++r)
            if (jo > il + r) s[nf][r] = -3e38f;
        }
      } else if (qt >= 8 && jt - jt0 < 2) {  // window-edge tiles (first two)
        int dl = (jt - jt0) << 6;
#pragma unroll
        for (int nf = 0; nf < 4; ++nf) {
          int jo = nf * 16 + fr + dl;
#pragma unroll
          for (int r = 0; r < 4; ++r)
            if (jo < il + r) s[nf][r] = -3e38f;
        }
      }
      // ---- online softmax (exp2 domain), defer-max rescale ----
      float tm[4];
#pragma unroll
      for (int r = 0; r < 4; ++r)
        tm[r] = fmaxf(fmaxf(s[0][r], s[1][r]), fmaxf(s[2][r], s[3][r]));
#pragma unroll
      for (int r = 0; r < 4; ++r) {
        tm[r] = fmaxf(tm[r], __shfl_xor(tm[r], 1));
        tm[r] = fmaxf(tm[r], __shfl_xor(tm[r], 2));
        tm[r] = fmaxf(tm[r], __shfl_xor(tm[r], 4));
        tm[r] = fmaxf(tm[r], __shfl_xor(tm[r], 8));
      }
      bool need = false;
#pragma unroll
      for (int r = 0; r < 4; ++r) need = need || (tm[r] > mrow[r] + 8.0f);
      if (__any(need)) {
#pragma unroll
        for (int r = 0; r < 4; ++r) {
          float mn = fmaxf(mrow[r], tm[r]);
          float sc = exp2f(mrow[r] - mn);
          mrow[r] = mn;
          lrow[r] *= sc;
#pragma unroll
          for (int of = 0; of < 8; ++of) o[of][r] *= sc;
        }
      }
      float ls[4] = {0.f, 0.f, 0.f, 0.f};
#pragma unroll
      for (int nf = 0; nf < 4; ++nf)
#pragma unroll
        for (int r = 0; r < 4; ++r) {
          float pv = exp2f(s[nf][r] - mrow[r]);
          s[nf][r] = pv;
          ls[r] += pv;
        }
#pragma unroll
      for (int r = 0; r < 4; ++r) {
        float t2 = ls[r];
        t2 += __shfl_xor(t2, 1); t2 += __shfl_xor(t2, 2);
        t2 += __shfl_xor(t2, 4); t2 += __shfl_xor(t2, 8);
        lrow[r] += t2;
      }
      // ---- P -> per-wave LDS (swizzled), wave-local ordering only ----
#pragma unroll
      for (int nf = 0; nf < 4; ++nf) {
        int sbase = (nf << 1) + (fr >> 3);
        int boff = (fr & 7) << 1;
#pragma unroll
        for (int r = 0; r < 4; ++r) {
          int q = (fq << 2) + r;
          *(f16*)(Psb + q * 128 + ((sbase ^ (q & 7)) << 4) + boff) = (f16)s[nf][r];
        }
      }
      asm volatile("s_waitcnt lgkmcnt(0)" ::: "memory");
      __builtin_amdgcn_sched_barrier(0);
      half8 pf0 = *(const half8*)(Psb + fr * 128 + (((fq) ^ (fr & 7)) << 4));
      half8 pf1 = *(const half8*)(Psb + fr * 128 + (((4 | fq) ^ (fr & 7)) << 4));
      // ---- O += P V ----
      __builtin_amdgcn_s_setprio(1);
#pragma unroll
      for (int of = 0; of < 8; ++of) {
        int vrow0 = of * 16 + fr;
        int sw = fr & 7;
        half8 v0 = *(const half8*)(Vsb + vrow0 * 128 + ((fq ^ sw) << 4));
        half8 v1 = *(const half8*)(Vsb + vrow0 * 128 + (((4 | fq) ^ sw) << 4));
        o[of] = __builtin_amdgcn_mfma_f32_16x16x32_f16(pf0, v0, o[of], 0, 0, 0);
        o[of] = __builtin_amdgcn_mfma_f32_16x16x32_f16(pf1, v1, o[of], 0, 0, 0);
      }
      __builtin_amdgcn_s_setprio(0);
    }
    __syncthreads();   // all waves done reading Ks/Vs before next stage
  }
  // ---- epilogue: normalize + silu(g), write (B,T,H,D) ----
  const f16* gb = gA + ((size_t)(b * T_SEQ) + iw) * NALL + COL_G + h * DH;
  float* ob = out + ((size_t)(b * T_SEQ) + iw) * DM + h * DH;
#pragma unroll
  for (int r = 0; r < 4; ++r) {
    float inv = 1.0f / lrow[r];
    int ir = fq * 4 + r;
#pragma unroll
    for (int of = 0; of < 8; ++of) {
      int d = of * 16 + fr;
      float gv = (float)gb[(size_t)ir * NALL + d];
      float sig = gv / (1.0f + expf(-gv));
      ob[(size_t)ir * DM + d] = o[of][r] * inv * sig;
    }
  }
}

extern "C" void kernel_launch(void* const* d_in, const int* in_sizes, int n_in,
                              void* d_out, int out_size, void* d_ws, size_t ws_size,
                              hipStream_t stream) {
  const float* x     = (const float*)d_in[0];
  const float* Wqkv  = (const float*)d_in[1];
  const float* Wrk   = (const float*)d_in[2];
  const float* brk   = (const float*)d_in[3];
  const float* sscal = (const float*)d_in[4];
  const float* Wg    = (const float*)d_in[5];
  float* out = (float*)d_out;
  char* ws = (char*)d_ws;
  size_t off = 0;
  auto alloc = [&](size_t bytes) -> void* {
    void* p = ws + off;
    off += (bytes + 255) & ~(size_t)255;
    return p;
  };
  f16* x16     = (f16*)alloc((size_t)M_ROWS * DM * 2);
  f16* BtAll   = (f16*)alloc((size_t)NALL * DM * 2);
  f16* CAll    = (f16*)alloc((size_t)M_ROWS * NALL * 2);
  f16* q16     = (f16*)alloc((size_t)B_SZ * NH * T_SEQ * DH * 2);
  f16* k16     = (f16*)alloc((size_t)B_SZ * NKV * T_SEQ * DH * 2);
  f16* v16     = (f16*)alloc((size_t)B_SZ * NKV * T_SEQ * DH * 2);
  f16* vt16    = (f16*)alloc((size_t)B_SZ * NKV * T_SEQ * DH * 2);

  k_cvt<<<(M_ROWS * DM / 4 + 255) / 256, 256, 0, stream>>>(x, x16, M_ROWS * DM);
  k_cvt_t<<<dim3(DM / 32, NQKV / 32), 256, 0, stream>>>(Wqkv, BtAll, DM, NQKV);
  k_cvt_t<<<dim3(DM / 32, 64 / 32), 256, 0, stream>>>(Wrk, BtAll + (size_t)COL_RK * DM, DM, 64);
  k_cvt_t<<<dim3(DM / 32, DM / 32), 256, 0, stream>>>(Wg, BtAll + (size_t)COL_G * DM, DM, DM);

  k_gemm_lds<<<dim3(NALL / 128, M_ROWS / 128), 256, 0, stream>>>(x16, BtAll, CAll, NALL, DM);

  k_postproc<<<M_ROWS, 256, 0, stream>>>(CAll, brk, sscal, q16, k16, v16);
  k_vt<<<dim3(T_SEQ / 32, DH / 32, B_SZ * NKV), 256, 0, stream>>>(v16, vt16);

  k_attn<<<dim3(T_SEQ / 128, NH, B_SZ), 512, 0, stream>>>(q16, k16, vt16, CAll, out);
}

// Round 5
// 359.957 us; speedup vs baseline: 1.3850x; 1.0202x over previous
//
#include <hip/hip_runtime.h>

typedef _Float16 f16;
typedef _Float16 half8 __attribute__((ext_vector_type(8)));
typedef _Float16 half4_t __attribute__((ext_vector_type(4)));
typedef float f32x4 __attribute__((ext_vector_type(4)));

#define T_SEQ 2048
#define B_SZ 2
#define DM 2048
#define NH 16
#define NKV 4
#define DH 128
#define NQKV 2560    // (16+4)*128
#define NALL 4736    // 2560 (qkv) + 128 (rk pad) + 2048 (gate)
#define NALLP 4864   // padded to 19*256 for the 256x128-tile GEMM grid
#define COL_RK 2560
#define COL_G 2688
#define M_ROWS 4096  // B*T
#define WIN 1024

typedef __attribute__((address_space(1))) const unsigned int guint;
typedef __attribute__((address_space(3))) unsigned int luint;
__device__ __forceinline__ void gload16(const void* g, void* l) {
  __builtin_amdgcn_global_load_lds((guint*)g, (luint*)l, 16, 0, 0);
}

// ---------------- fp32 -> f16 elementwise ----------------
__global__ void k_cvt(const float* __restrict__ in, f16* __restrict__ out, int n) {
  int i = (blockIdx.x * 256 + threadIdx.x) * 4;
  if (i >= n) return;
  float4 v = *(const float4*)(in + i);
  half4_t o;
  o[0] = (f16)v.x; o[1] = (f16)v.y; o[2] = (f16)v.z; o[3] = (f16)v.w;
  *(half4_t*)(out + i) = o;
}

// ---------------- fp32 (K,N) -> f16 (N,K) transpose-convert ----------------
__global__ __launch_bounds__(256) void k_cvt_t(const float* __restrict__ W,
                                               f16* __restrict__ Wt, int K, int N) {
  __shared__ float tile[32][33];
  int k0 = blockIdx.x * 32, n0 = blockIdx.y * 32;
  int tx = threadIdx.x & 31, ty = threadIdx.x >> 5; // 32 x 8
#pragma unroll
  for (int r = 0; r < 32; r += 8)
    tile[ty + r][tx] = W[(size_t)(k0 + ty + r) * N + n0 + tx];
  __syncthreads();
#pragma unroll
  for (int r = 0; r < 32; r += 8)
    Wt[(size_t)(n0 + ty + r) * K + k0 + tx] = (f16)tile[tx][ty + r];
}

// ---------------- f16 [T][128] -> f16 [128][T] per matrix ----------------
__global__ __launch_bounds__(256) void k_vt(const f16* __restrict__ v, f16* __restrict__ vt) {
  __shared__ f16 tile[32][34];
  int t0 = blockIdx.x * 32, d0 = blockIdx.y * 32, m = blockIdx.z;
  int tx = threadIdx.x & 31, ty = threadIdx.x >> 5;
  const f16* src = v + (size_t)m * T_SEQ * DH;
  f16* dst = vt + (size_t)m * T_SEQ * DH;
#pragma unroll
  for (int r = 0; r < 32; r += 8)
    tile[ty + r][tx] = src[(size_t)(t0 + ty + r) * DH + d0 + tx];
  __syncthreads();
#pragma unroll
  for (int r = 0; r < 32; r += 8)
    dst[(size_t)(d0 + ty + r) * T_SEQ + t0 + tx] = tile[tx][ty + r];
}

// ======== 8-phase-style pipelined GEMM: C[M,NALLP](f16) = A[M,K] * Bt[NALLP,K]^T ========
// BM=256, BN=128, BK=64 (2 kk-phases of 32), 8 waves (4M x 2N), wave tile 64x64.
// LDS 96KB: A [2buf][2kk][256 rows][64B], B at +65536 [2buf][2kk][128 rows][64B].
// Bank swizzle: 16B-slot ^= (row>>1)&3  (applied to gload SOURCE + ds_read addr;
// LDS dest stays linear — global_load_lds writes base+lane*16).
// Counted vmcnt(3) at every phase end: the 3 staging loads of the NEXT kk-half
// stay in flight across the barrier; never drains to 0 in the main loop.
#define GEMM_PHASE(cb, kk, sb, koff)                                                        \
  {                                                                                         \
    char* Ab = lds + (cb) * 32768 + (kk) * 16384;                                           \
    char* Bb = lds + 65536 + (cb) * 16384 + (kk) * 8192;                                    \
    half8 af[4], bf[4];                                                                     \
    _Pragma("unroll")                                                                       \
    for (int i = 0; i < 4; ++i)                                                             \
      af[i] = *(const half8*)(Ab + (wm * 64 + i * 16 + fr) * 64 + xsl);                     \
    _Pragma("unroll")                                                                       \
    for (int j = 0; j < 4; ++j)                                                             \
      bf[j] = *(const half8*)(Bb + (wn * 64 + j * 16 + fr) * 64 + xsl);                     \
    gload16(Ag0 + (koff) + (kk) * 32, lds + (sb) * 32768 + (kk) * 16384 + w * 1024);        \
    gload16(Ag1 + (koff) + (kk) * 32, lds + (sb) * 32768 + (kk) * 16384 + 8192 + w * 1024); \
    gload16(Bg + (koff) + (kk) * 32, lds + 65536 + (sb) * 16384 + (kk) * 8192 + w * 1024);  \
    __builtin_amdgcn_s_barrier();                                                           \
    __builtin_amdgcn_sched_barrier(0);                                                      \
    asm volatile("s_waitcnt lgkmcnt(0)" ::: "memory");                                      \
    __builtin_amdgcn_sched_barrier(0);                                                      \
    __builtin_amdgcn_s_setprio(1);                                                          \
    _Pragma("unroll")                                                                       \
    for (int i = 0; i < 4; ++i)                                                             \
      _Pragma("unroll")                                                                     \
      for (int j = 0; j < 4; ++j)                                                           \
        acc[i][j] = __builtin_amdgcn_mfma_f32_16x16x32_f16(af[i], bf[j], acc[i][j], 0, 0, 0); \
    __builtin_amdgcn_s_setprio(0);                                                          \
    asm volatile("s_waitcnt vmcnt(3)" ::: "memory");                                        \
    __builtin_amdgcn_s_barrier();                                                           \
    __builtin_amdgcn_sched_barrier(0);                                                      \
  }

__global__ __launch_bounds__(512, 2) void k_gemm8(const f16* __restrict__ A,
                                                  const f16* __restrict__ Bt,
                                                  f16* __restrict__ C) {
  __shared__ __align__(16) char lds[98304];
  const int K = DM;
  // bijective XCD swizzle: nwg = 38*16 = 608 = 8*76
  unsigned orig = blockIdx.y * 38u + blockIdx.x;
  unsigned swz = (orig & 7u) * 76u + (orig >> 3);
  int m0 = (int)(swz / 38u) * 256;
  int n0 = (int)(swz % 38u) * 128;
  int tid = threadIdx.x, lane = tid & 63, w = tid >> 6;
  int wm = w >> 1, wn = w & 1;
  int fr = lane & 15, fq = lane >> 4;
  int xsl = (fq ^ ((fr >> 1) & 3)) << 4;       // read-side swizzled 16B slot
  int sr = tid >> 2, ss = tid & 3;             // staging: row-in-chunk, LDS slot
  int scol = (ss ^ ((sr >> 1) & 3)) * 8;       // inverse-swizzled source col (f16)
  f32x4 acc[4][4] = {};
  const f16* Ag0 = A + (size_t)(m0 + sr) * K + scol;        // rows 0..127 of A-tile
  const f16* Ag1 = A + (size_t)(m0 + 128 + sr) * K + scol;  // rows 128..255
  const f16* Bg  = Bt + (size_t)(n0 + sr) * K + scol;       // rows 0..127 of B-tile

  // prologue: stage tile 0 fully (6 loads), wait until kk0's 3 landed
  gload16(Ag0, lds + w * 1024);
  gload16(Ag1, lds + 8192 + w * 1024);
  gload16(Bg, lds + 65536 + w * 1024);
  gload16(Ag0 + 32, lds + 16384 + w * 1024);
  gload16(Ag1 + 32, lds + 16384 + 8192 + w * 1024);
  gload16(Bg + 32, lds + 65536 + 8192 + w * 1024);
  asm volatile("s_waitcnt vmcnt(3)" ::: "memory");
  __builtin_amdgcn_s_barrier();
  __builtin_amdgcn_sched_barrier(0);

  for (int kt = 0; kt < 32; ++kt) {
    int cb = kt & 1;
    int nt = kt < 31 ? kt + 1 : 31;   // last iter re-stages tile 31 (identical bytes: benign)
    int sb = nt & 1;
    int koff = nt * 64;
    GEMM_PHASE(cb, 0, sb, koff);
    GEMM_PHASE(cb, 1, sb, koff);
  }

#pragma unroll
  for (int i = 0; i < 4; ++i) {
    int row = m0 + wm * 64 + i * 16 + fq * 4;
#pragma unroll
    for (int j = 0; j < 4; ++j) {
      int col = n0 + wn * 64 + j * 16 + fr;
      f16* Cp = C + (size_t)row * NALLP + col;
#pragma unroll
      for (int rr = 0; rr < 4; ++rr) Cp[(size_t)rr * NALLP] = (f16)acc[i][j][rr];
    }
  }
}

// ---------------- RMSNorm + RoPE + scale + pack q/k/v as f16 ----------------
__global__ __launch_bounds__(256) void k_postproc(
    const f16* __restrict__ CA,
    const float* __restrict__ brk, const float* __restrict__ sscal,
    f16* __restrict__ q16, f16* __restrict__ k16, f16* __restrict__ v16) {
  int row = blockIdx.x;              // b*T + t
  int b = row >> 11, t = row & 2047;
  int lane = threadIdx.x & 63, wid = threadIdx.x >> 6;
  int ridx = lane & 31;
  float inv_freq = powf(10000.0f, -(float)(2 * ridx) / 64.0f);
  float fr = (float)t * inv_freq;
  float cs = cosf(fr), sn = sinf(fr);
  float logpos = logf(fminf((float)(t + 1), 1024.0f));
  // 1/sqrt(128) * log2(e): attention works in exp2 domain
  const float rsqrt_d_log2e = 0.08838834764831845f * 1.4426950408889634f;
  const f16* Crow = CA + (size_t)row * NALLP;
#pragma unroll
  for (int p = 0; p < 5; ++p) {
    int h = p * 4 + wid; // 0..19
    float v0 = (float)Crow[h * 128 + lane];
    float v1 = (float)Crow[h * 128 + 64 + lane];
    float ss = v0 * v0 + v1 * v1;
#pragma unroll
    for (int m = 1; m < 64; m <<= 1) ss += __shfl_xor(ss, m);
    float rms = rsqrtf(ss * (1.0f / 128.0f) + 1e-6f);
    v0 *= rms; v1 *= rms;
    if (h < NH) {
      float part = __shfl_xor(v1, 32);
      float vr = (lane < 32) ? (v1 * cs + part * sn) : (v1 * cs - part * sn);
      float scale = sscal[h] * logpos * rsqrt_d_log2e;
      size_t qb = ((size_t)(b * NH + h) * T_SEQ + t) * DH;
      q16[qb + lane]      = (f16)(v0 * scale);
      q16[qb + 64 + lane] = (f16)(vr * scale);
    } else {
      int hk = h - NH;
      size_t kb = ((size_t)(b * NKV + hk) * T_SEQ + t) * DH;
      k16[kb + lane]      = (f16)v0;  // tied kv
      v16[kb + lane]      = (f16)v0;  // tied kv
      v16[kb + 64 + lane] = (f16)v1;  // v
    }
  }
  if (wid == 0) {
    float kr = (float)Crow[COL_RK + lane] + brk[lane];
    float part = __shfl_xor(kr, 32);
    float vr = (lane < 32) ? (kr * cs + part * sn) : (kr * cs - part * sn);
    f16 hv = (f16)vr;
#pragma unroll
    for (int hk = 0; hk < NKV; ++hk)
      k16[((size_t)(b * NKV + hk) * T_SEQ + t) * DH + 64 + lane] = hv;
  }
}

// ---------------- sliding-window flash attention + silu(g) epilogue ----------------
// BQ=128 (8 waves x 16 q-rows), KV tile 64.
// NOTE: launch_bounds min-waves MUST stay low — (512,6) capped VGPRs at 40 and
// spilled the o[] accumulator to scratch (440MB fetch, 2.3x slowdown, round 3).
__global__ __launch_bounds__(512, 2) void k_attn(
    const f16* __restrict__ q16, const f16* __restrict__ k16, const f16* __restrict__ vt16,
    const f16* __restrict__ gA, float* __restrict__ out) {
  __shared__ __align__(16) f16 Ks[64 * DH];
  __shared__ __align__(16) f16 Vs[DH * 64];
  __shared__ __align__(16) f16 Ps[8 * 16 * 64];
  int bx = blockIdx.x;
  int qt = (bx & 1) ? (15 - (bx >> 1)) : (bx >> 1);  // load-balance heavy/light tiles
  int h = blockIdx.y, b = blockIdx.z, hk = h >> 2;
  int tid = threadIdx.x, lane = tid & 63, w = tid >> 6;
  int i0 = qt * 128, iw = i0 + w * 16;
  int fr = lane & 15, fq = lane >> 4;

  char* Ksb = (char*)Ks;
  char* Vsb = (char*)Vs;
  char* Psb = (char*)Ps + w * 2048;

  const f16* qbase = q16 + ((size_t)(b * NH + h) * T_SEQ + iw + fr) * DH;
  half8 qf[4];
#pragma unroll
  for (int kb = 0; kb < 4; ++kb) qf[kb] = *(const half8*)&qbase[kb * 32 + fq * 8];

  f32x4 o[8] = {};
  float mrow[4] = {-1e30f, -1e30f, -1e30f, -1e30f};
  float lrow[4] = {0.f, 0.f, 0.f, 0.f};

  const f16* kg = k16 + (size_t)(b * NKV + hk) * T_SEQ * DH;   // [T][128]
  const f16* vg = vt16 + (size_t)(b * NKV + hk) * T_SEQ * DH;  // [128][T]

  int jtTop = qt * 2 + 1;
  int jt0 = qt >= 8 ? qt * 2 - 16 : 0;
  for (int jt = jt0; jt <= jtTop; ++jt) {
    int j0 = jt * 64;
    // ---- stage K (16KB) + V^T (16KB), inverse-swizzled source, linear LDS dest ----
#pragma unroll
    for (int i = 0; i < 2; ++i) {
      int r = i * 32 + (tid >> 4);
      int c = (tid & 15) ^ (r & 7);
      gload16(kg + (size_t)(j0 + r) * DH + c * 8, Ksb + i * 8192 + w * 1024);
    }
#pragma unroll
    for (int i = 0; i < 2; ++i) {
      int r = i * 64 + (tid >> 3);
      int c = (tid & 7) ^ (r & 7);
      gload16(vg + (size_t)r * T_SEQ + j0 + c * 8, Vsb + i * 8192 + w * 1024);
    }
    __syncthreads();   // drains vmcnt(0): tiles resident

    // full-masked wave skip on boundary tiles
    bool active = (jt == jtTop) ? (w >= 4)
                : ((qt >= 8 && jt == jt0) ? (w < 4) : true);
    if (active) {
      // ---- S = Q K^T (16 q-rows x 64 keys per wave) ----
      f32x4 s[4] = {};
      __builtin_amdgcn_s_setprio(1);
#pragma unroll
      for (int nf = 0; nf < 4; ++nf) {
        int row = nf * 16 + fr;
        int sw = fr & 7;
#pragma unroll
        for (int kb = 0; kb < 4; ++kb) {
          half8 bfv = *(const half8*)(Ksb + row * 256 + ((((kb << 2) | fq) ^ sw) << 4));
          s[nf] = __builtin_amdgcn_mfma_f32_16x16x32_f16(qf[kb], bfv, s[nf], 0, 0, 0);
        }
      }
      __builtin_amdgcn_s_setprio(0);
      // ---- masking ----
      int il = (w << 4) + (fq << 2);
      if (jt >= (qt << 1)) {            // causal tiles (last two)
        int dc = (jt << 6) - i0;
#pragma unroll
        for (int nf = 0; nf < 4; ++nf) {
          int jo = nf * 16 + fr + dc;
#pragma unroll
          for (int r = 0; r < 4; ++r)
            if (jo > il + r) s[nf][r] = -3e38f;
        }
      } else if (qt >= 8 && jt - jt0 < 2) {  // window-edge tiles (first two)
        int dl = (jt - jt0) << 6;
#pragma unroll
        for (int nf = 0; nf < 4; ++nf) {
          int jo = nf * 16 + fr + dl;
#pragma unroll
          for (int r = 0; r < 4; ++r)
            if (jo < il + r) s[nf][r] = -3e38f;
        }
      }
      // ---- online softmax (exp2 domain), defer-max rescale ----
      float tm[4];
#pragma unroll
      for (int r = 0; r < 4; ++r)
        tm[r] = fmaxf(fmaxf(s[0][r], s[1][r]), fmaxf(s[2][r], s[3][r]));
#pragma unroll
      for (int r = 0; r < 4; ++r) {
        tm[r] = fmaxf(tm[r], __shfl_xor(tm[r], 1));
        tm[r] = fmaxf(tm[r], __shfl_xor(tm[r], 2));
        tm[r] = fmaxf(tm[r], __shfl_xor(tm[r], 4));
        tm[r] = fmaxf(tm[r], __shfl_xor(tm[r], 8));
      }
      bool need = false;
#pragma unroll
      for (int r = 0; r < 4; ++r) need = need || (tm[r] > mrow[r] + 8.0f);
      if (__any(need)) {
#pragma unroll
        for (int r = 0; r < 4; ++r) {
          float mn = fmaxf(mrow[r], tm[r]);
          float sc = exp2f(mrow[r] - mn);
          mrow[r] = mn;
          lrow[r] *= sc;
#pragma unroll
          for (int of = 0; of < 8; ++of) o[of][r] *= sc;
        }
      }
      float ls[4] = {0.f, 0.f, 0.f, 0.f};
#pragma unroll
      for (int nf = 0; nf < 4; ++nf)
#pragma unroll
        for (int r = 0; r < 4; ++r) {
          float pv = exp2f(s[nf][r] - mrow[r]);
          s[nf][r] = pv;
          ls[r] += pv;
        }
#pragma unroll
      for (int r = 0; r < 4; ++r) {
        float t2 = ls[r];
        t2 += __shfl_xor(t2, 1); t2 += __shfl_xor(t2, 2);
        t2 += __shfl_xor(t2, 4); t2 += __shfl_xor(t2, 8);
        lrow[r] += t2;
      }
      // ---- P -> per-wave LDS (swizzled), wave-local ordering only ----
#pragma unroll
      for (int nf = 0; nf < 4; ++nf) {
        int sbase = (nf << 1) + (fr >> 3);
        int boff = (fr & 7) << 1;
#pragma unroll
        for (int r = 0; r < 4; ++r) {
          int q = (fq << 2) + r;
          *(f16*)(Psb + q * 128 + ((sbase ^ (q & 7)) << 4) + boff) = (f16)s[nf][r];
        }
      }
      asm volatile("s_waitcnt lgkmcnt(0)" ::: "memory");
      __builtin_amdgcn_sched_barrier(0);
      half8 pf0 = *(const half8*)(Psb + fr * 128 + (((fq) ^ (fr & 7)) << 4));
      half8 pf1 = *(const half8*)(Psb + fr * 128 + (((4 | fq) ^ (fr & 7)) << 4));
      // ---- O += P V ----
      __builtin_amdgcn_s_setprio(1);
#pragma unroll
      for (int of = 0; of < 8; ++of) {
        int vrow0 = of * 16 + fr;
        int sw = fr & 7;
        half8 v0 = *(const half8*)(Vsb + vrow0 * 128 + ((fq ^ sw) << 4));
        half8 v1 = *(const half8*)(Vsb + vrow0 * 128 + (((4 | fq) ^ sw) << 4));
        o[of] = __builtin_amdgcn_mfma_f32_16x16x32_f16(pf0, v0, o[of], 0, 0, 0);
        o[of] = __builtin_amdgcn_mfma_f32_16x16x32_f16(pf1, v1, o[of], 0, 0, 0);
      }
      __builtin_amdgcn_s_setprio(0);
    }
    __syncthreads();   // all waves done reading Ks/Vs before next stage
  }
  // ---- epilogue: normalize + silu(g), write (B,T,H,D) ----
  const f16* gb = gA + ((size_t)(b * T_SEQ) + iw) * NALLP + COL_G + h * DH;
  float* ob = out + ((size_t)(b * T_SEQ) + iw) * DM + h * DH;
#pragma unroll
  for (int r = 0; r < 4; ++r) {
    float inv = 1.0f / lrow[r];
    int ir = fq * 4 + r;
#pragma unroll
    for (int of = 0; of < 8; ++of) {
      int d = of * 16 + fr;
      float gv = (float)gb[(size_t)ir * NALLP + d];
      float sig = gv / (1.0f + expf(-gv));
      ob[(size_t)ir * DM + d] = o[of][r] * inv * sig;
    }
  }
}

extern "C" void kernel_launch(void* const* d_in, const int* in_sizes, int n_in,
                              void* d_out, int out_size, void* d_ws, size_t ws_size,
                              hipStream_t stream) {
  const float* x     = (const float*)d_in[0];
  const float* Wqkv  = (const float*)d_in[1];
  const float* Wrk   = (const float*)d_in[2];
  const float* brk   = (const float*)d_in[3];
  const float* sscal = (const float*)d_in[4];
  const float* Wg    = (const float*)d_in[5];
  float* out = (float*)d_out;
  char* ws = (char*)d_ws;
  size_t off = 0;
  auto alloc = [&](size_t bytes) -> void* {
    void* p = ws + off;
    off += (bytes + 255) & ~(size_t)255;
    return p;
  };
  f16* x16     = (f16*)alloc((size_t)M_ROWS * DM * 2);
  f16* BtAll   = (f16*)alloc((size_t)NALLP * DM * 2);
  f16* CAll    = (f16*)alloc((size_t)M_ROWS * NALLP * 2);
  f16* q16     = (f16*)alloc((size_t)B_SZ * NH * T_SEQ * DH * 2);
  f16* k16     = (f16*)alloc((size_t)B_SZ * NKV * T_SEQ * DH * 2);
  f16* v16     = (f16*)alloc((size_t)B_SZ * NKV * T_SEQ * DH * 2);
  f16* vt16    = (f16*)alloc((size_t)B_SZ * NKV * T_SEQ * DH * 2);

  k_cvt<<<(M_ROWS * DM / 4 + 255) / 256, 256, 0, stream>>>(x, x16, M_ROWS * DM);
  k_cvt_t<<<dim3(DM / 32, NQKV / 32), 256, 0, stream>>>(Wqkv, BtAll, DM, NQKV);
  k_cvt_t<<<dim3(DM / 32, 64 / 32), 256, 0, stream>>>(Wrk, BtAll + (size_t)COL_RK * DM, DM, 64);
  k_cvt_t<<<dim3(DM / 32, DM / 32), 256, 0, stream>>>(Wg, BtAll + (size_t)COL_G * DM, DM, DM);

  k_gemm8<<<dim3(NALLP / 128, M_ROWS / 256), 512, 0, stream>>>(x16, BtAll, CAll);

  k_postproc<<<M_ROWS, 256, 0, stream>>>(CAll, brk, sscal, q16, k16, v16);
  k_vt<<<dim3(T_SEQ / 32, DH / 32, B_SZ * NKV), 256, 0, stream>>>(v16, vt16);

  k_attn<<<dim3(T_SEQ / 128, NH, B_SZ), 512, 0, stream>>>(q16, k16, vt16, CAll, out);
}

// Round 6
// 348.447 us; speedup vs baseline: 1.4307x; 1.0330x over previous
//
#include <hip/hip_runtime.h>

typedef _Float16 f16;
typedef _Float16 half8 __attribute__((ext_vector_type(8)));
typedef _Float16 half4_t __attribute__((ext_vector_type(4)));
typedef float f32x4 __attribute__((ext_vector_type(4)));

#define T_SEQ 2048
#define B_SZ 2
#define DM 2048
#define NH 16
#define NKV 4
#define DH 128
#define NQKV 2560    // (16+4)*128
#define NALL 4736    // 2560 (qkv) + 128 (rk pad) + 2048 (gate)
#define NALLP 4864   // padded to 19*256 for the 256x128-tile GEMM grid
#define COL_RK 2560
#define COL_G 2688
#define M_ROWS 4096  // B*T
#define WIN 1024

typedef __attribute__((address_space(1))) const unsigned int guint;
typedef __attribute__((address_space(3))) unsigned int luint;
__device__ __forceinline__ void gload16(const void* g, void* l) {
  __builtin_amdgcn_global_load_lds((guint*)g, (luint*)l, 16, 0, 0);
}

// ---------------- fp32 -> f16 elementwise ----------------
__global__ void k_cvt(const float* __restrict__ in, f16* __restrict__ out, int n) {
  int i = (blockIdx.x * 256 + threadIdx.x) * 4;
  if (i >= n) return;
  float4 v = *(const float4*)(in + i);
  half4_t o;
  o[0] = (f16)v.x; o[1] = (f16)v.y; o[2] = (f16)v.z; o[3] = (f16)v.w;
  *(half4_t*)(out + i) = o;
}

// ---------------- fp32 (K,N) -> f16 (N,K) transpose-convert ----------------
__global__ __launch_bounds__(256) void k_cvt_t(const float* __restrict__ W,
                                               f16* __restrict__ Wt, int K, int N) {
  __shared__ float tile[32][33];
  int k0 = blockIdx.x * 32, n0 = blockIdx.y * 32;
  int tx = threadIdx.x & 31, ty = threadIdx.x >> 5; // 32 x 8
#pragma unroll
  for (int r = 0; r < 32; r += 8)
    tile[ty + r][tx] = W[(size_t)(k0 + ty + r) * N + n0 + tx];
  __syncthreads();
#pragma unroll
  for (int r = 0; r < 32; r += 8)
    Wt[(size_t)(n0 + ty + r) * K + k0 + tx] = (f16)tile[tx][ty + r];
}

// ---------------- f16 [T][128] -> f16 [128][T] per matrix ----------------
__global__ __launch_bounds__(256) void k_vt(const f16* __restrict__ v, f16* __restrict__ vt) {
  __shared__ f16 tile[32][34];
  int t0 = blockIdx.x * 32, d0 = blockIdx.y * 32, m = blockIdx.z;
  int tx = threadIdx.x & 31, ty = threadIdx.x >> 5;
  const f16* src = v + (size_t)m * T_SEQ * DH;
  f16* dst = vt + (size_t)m * T_SEQ * DH;
#pragma unroll
  for (int r = 0; r < 32; r += 8)
    tile[ty + r][tx] = src[(size_t)(t0 + ty + r) * DH + d0 + tx];
  __syncthreads();
#pragma unroll
  for (int r = 0; r < 32; r += 8)
    dst[(size_t)(d0 + ty + r) * T_SEQ + t0 + tx] = tile[tx][ty + r];
}

// ======== 8-phase-style pipelined GEMM: C[M,NALLP](f16) = A[M,K] * Bt[NALLP,K]^T ========
// BM=256, BN=128, BK=64 (2 kk-phases of 32), 8 waves (4M x 2N), wave tile 64x64.
// Counted vmcnt(3): next kk-half's 3 staging loads stay in flight across the barrier.
#define GEMM_PHASE(cb, kk, sb, koff)                                                        \
  {                                                                                         \
    char* Ab = lds + (cb) * 32768 + (kk) * 16384;                                           \
    char* Bb = lds + 65536 + (cb) * 16384 + (kk) * 8192;                                    \
    half8 af[4], bf[4];                                                                     \
    _Pragma("unroll")                                                                       \
    for (int i = 0; i < 4; ++i)                                                             \
      af[i] = *(const half8*)(Ab + (wm * 64 + i * 16 + fr) * 64 + xsl);                     \
    _Pragma("unroll")                                                                       \
    for (int j = 0; j < 4; ++j)                                                             \
      bf[j] = *(const half8*)(Bb + (wn * 64 + j * 16 + fr) * 64 + xsl);                     \
    gload16(Ag0 + (koff) + (kk) * 32, lds + (sb) * 32768 + (kk) * 16384 + w * 1024);        \
    gload16(Ag1 + (koff) + (kk) * 32, lds + (sb) * 32768 + (kk) * 16384 + 8192 + w * 1024); \
    gload16(Bg + (koff) + (kk) * 32, lds + 65536 + (sb) * 16384 + (kk) * 8192 + w * 1024);  \
    __builtin_amdgcn_s_barrier();                                                           \
    __builtin_amdgcn_sched_barrier(0);                                                      \
    asm volatile("s_waitcnt lgkmcnt(0)" ::: "memory");                                      \
    __builtin_amdgcn_sched_barrier(0);                                                      \
    __builtin_amdgcn_s_setprio(1);                                                          \
    _Pragma("unroll")                                                                       \
    for (int i = 0; i < 4; ++i)                                                             \
      _Pragma("unroll")                                                                     \
      for (int j = 0; j < 4; ++j)                                                           \
        acc[i][j] = __builtin_amdgcn_mfma_f32_16x16x32_f16(af[i], bf[j], acc[i][j], 0, 0, 0); \
    __builtin_amdgcn_s_setprio(0);                                                          \
    asm volatile("s_waitcnt vmcnt(3)" ::: "memory");                                        \
    __builtin_amdgcn_s_barrier();                                                           \
    __builtin_amdgcn_sched_barrier(0);                                                      \
  }

__global__ __launch_bounds__(512, 2) void k_gemm8(const f16* __restrict__ A,
                                                  const f16* __restrict__ Bt,
                                                  f16* __restrict__ C) {
  __shared__ __align__(16) char lds[98304];
  const int K = DM;
  // bijective XCD swizzle: nwg = 38*16 = 608 = 8*76
  unsigned orig = blockIdx.y * 38u + blockIdx.x;
  unsigned swz = (orig & 7u) * 76u + (orig >> 3);
  int m0 = (int)(swz / 38u) * 256;
  int n0 = (int)(swz % 38u) * 128;
  int tid = threadIdx.x, lane = tid & 63, w = tid >> 6;
  int wm = w >> 1, wn = w & 1;
  int fr = lane & 15, fq = lane >> 4;
  int xsl = (fq ^ ((fr >> 1) & 3)) << 4;       // read-side swizzled 16B slot
  int sr = tid >> 2, ss = tid & 3;             // staging: row-in-chunk, LDS slot
  int scol = (ss ^ ((sr >> 1) & 3)) * 8;       // inverse-swizzled source col (f16)
  f32x4 acc[4][4] = {};
  const f16* Ag0 = A + (size_t)(m0 + sr) * K + scol;        // rows 0..127 of A-tile
  const f16* Ag1 = A + (size_t)(m0 + 128 + sr) * K + scol;  // rows 128..255
  const f16* Bg  = Bt + (size_t)(n0 + sr) * K + scol;       // rows 0..127 of B-tile

  // prologue: stage tile 0 fully (6 loads), wait until kk0's 3 landed
  gload16(Ag0, lds + w * 1024);
  gload16(Ag1, lds + 8192 + w * 1024);
  gload16(Bg, lds + 65536 + w * 1024);
  gload16(Ag0 + 32, lds + 16384 + w * 1024);
  gload16(Ag1 + 32, lds + 16384 + 8192 + w * 1024);
  gload16(Bg + 32, lds + 65536 + 8192 + w * 1024);
  asm volatile("s_waitcnt vmcnt(3)" ::: "memory");
  __builtin_amdgcn_s_barrier();
  __builtin_amdgcn_sched_barrier(0);

  for (int kt = 0; kt < 32; ++kt) {
    int cb = kt & 1;
    int nt = kt < 31 ? kt + 1 : 31;   // last iter re-stages tile 31 (identical bytes: benign)
    int sb = nt & 1;
    int koff = nt * 64;
    GEMM_PHASE(cb, 0, sb, koff);
    GEMM_PHASE(cb, 1, sb, koff);
  }

#pragma unroll
  for (int i = 0; i < 4; ++i) {
    int row = m0 + wm * 64 + i * 16 + fq * 4;
#pragma unroll
    for (int j = 0; j < 4; ++j) {
      int col = n0 + wn * 64 + j * 16 + fr;
      f16* Cp = C + (size_t)row * NALLP + col;
#pragma unroll
      for (int rr = 0; rr < 4; ++rr) Cp[(size_t)rr * NALLP] = (f16)acc[i][j][rr];
    }
  }
}

// ---------------- RMSNorm + RoPE + scale + pack q/k/v as f16 ----------------
__global__ __launch_bounds__(256) void k_postproc(
    const f16* __restrict__ CA,
    const float* __restrict__ brk, const float* __restrict__ sscal,
    f16* __restrict__ q16, f16* __restrict__ k16, f16* __restrict__ v16) {
  int row = blockIdx.x;              // b*T + t
  int b = row >> 11, t = row & 2047;
  int lane = threadIdx.x & 63, wid = threadIdx.x >> 6;
  int ridx = lane & 31;
  float inv_freq = powf(10000.0f, -(float)(2 * ridx) / 64.0f);
  float fr = (float)t * inv_freq;
  float cs = cosf(fr), sn = sinf(fr);
  float logpos = logf(fminf((float)(t + 1), 1024.0f));
  // 1/sqrt(128) * log2(e): attention works in exp2 domain
  const float rsqrt_d_log2e = 0.08838834764831845f * 1.4426950408889634f;
  const f16* Crow = CA + (size_t)row * NALLP;
#pragma unroll
  for (int p = 0; p < 5; ++p) {
    int h = p * 4 + wid; // 0..19
    float v0 = (float)Crow[h * 128 + lane];
    float v1 = (float)Crow[h * 128 + 64 + lane];
    float ss = v0 * v0 + v1 * v1;
#pragma unroll
    for (int m = 1; m < 64; m <<= 1) ss += __shfl_xor(ss, m);
    float rms = rsqrtf(ss * (1.0f / 128.0f) + 1e-6f);
    v0 *= rms; v1 *= rms;
    if (h < NH) {
      float part = __shfl_xor(v1, 32);
      float vr = (lane < 32) ? (v1 * cs + part * sn) : (v1 * cs - part * sn);
      float scale = sscal[h] * logpos * rsqrt_d_log2e;
      size_t qb = ((size_t)(b * NH + h) * T_SEQ + t) * DH;
      q16[qb + lane]      = (f16)(v0 * scale);
      q16[qb + 64 + lane] = (f16)(vr * scale);
    } else {
      int hk = h - NH;
      size_t kb = ((size_t)(b * NKV + hk) * T_SEQ + t) * DH;
      k16[kb + lane]      = (f16)v0;  // tied kv
      v16[kb + lane]      = (f16)v0;  // tied kv
      v16[kb + 64 + lane] = (f16)v1;  // v
    }
  }
  if (wid == 0) {
    float kr = (float)Crow[COL_RK + lane] + brk[lane];
    float part = __shfl_xor(kr, 32);
    float vr = (lane < 32) ? (kr * cs + part * sn) : (kr * cs - part * sn);
    f16 hv = (f16)vr;
#pragma unroll
    for (int hk = 0; hk < NKV; ++hk)
      k16[((size_t)(b * NKV + hk) * T_SEQ + t) * DH + 64 + lane] = hv;
  }
}

// ---------------- sliding-window flash attention + silu(g) epilogue ----------------
// BQ=128 (8 waves x 16 q-rows), KV tile 64, DOUBLE-BUFFERED K/V staging:
// STAGE(next) issued before compute(cur); one vmcnt(0)+barrier per tile.
// LDS 80KB: Kbuf[c]=c*32768 ([64][128] swz rows), Vbuf[c]=+16384 ([128][64] swz),
// P at 65536 (per-wave 2KB). 80KB -> exactly 2 blocks/CU (matches grid 512/256CU).
// NOTE: launch_bounds min-waves MUST stay low — (512,6) capped VGPRs at 40 and
// spilled the o[] accumulator to scratch (440MB fetch, 2.3x slowdown, round 3).
__global__ __launch_bounds__(512, 2) void k_attn(
    const f16* __restrict__ q16, const f16* __restrict__ k16, const f16* __restrict__ vt16,
    const f16* __restrict__ gA, float* __restrict__ out) {
  __shared__ __align__(16) char lds[81920];
  int bx = blockIdx.x;
  int qt = (bx & 1) ? (15 - (bx >> 1)) : (bx >> 1);  // load-balance heavy/light tiles
  int h = blockIdx.y, b = blockIdx.z, hk = h >> 2;
  int tid = threadIdx.x, lane = tid & 63, w = tid >> 6;
  int i0 = qt * 128, iw = i0 + w * 16;
  int fr = lane & 15, fq = lane >> 4;

  char* Psb = lds + 65536 + w * 2048;

  const f16* qbase = q16 + ((size_t)(b * NH + h) * T_SEQ + iw + fr) * DH;
  half8 qf[4];
#pragma unroll
  for (int kb = 0; kb < 4; ++kb) qf[kb] = *(const half8*)&qbase[kb * 32 + fq * 8];

  f32x4 o[8] = {};
  float mrow[4] = {-1e30f, -1e30f, -1e30f, -1e30f};
  float lrow[4] = {0.f, 0.f, 0.f, 0.f};

  const f16* kg = k16 + (size_t)(b * NKV + hk) * T_SEQ * DH;   // [T][128]
  const f16* vg = vt16 + (size_t)(b * NKV + hk) * T_SEQ * DH;  // [128][T]

  int jtTop = qt * 2 + 1;
  int jt0 = qt >= 8 ? qt * 2 - 16 : 0;

  // staging lane coords (inverse-swizzled source, linear LDS dest)
  int kr_ = tid >> 4, kc_ = ((tid & 15) ^ (kr_ & 7)) * 8;
  int vr_ = tid >> 3, vc_ = ((tid & 7) ^ (vr_ & 7)) * 8;

  auto STAGE = [&](int cbuf, int j0) {
    char* Kb = lds + cbuf * 32768;
    char* Vb = lds + cbuf * 32768 + 16384;
#pragma unroll
    for (int i = 0; i < 2; ++i)
      gload16(kg + (size_t)(j0 + i * 32 + kr_) * DH + kc_, Kb + i * 8192 + w * 1024);
#pragma unroll
    for (int i = 0; i < 2; ++i)
      gload16(vg + (size_t)(i * 64 + vr_) * T_SEQ + j0 + vc_, Vb + i * 8192 + w * 1024);
  };

  // prologue: stage first tile
  STAGE(0, jt0 * 64);
  asm volatile("s_waitcnt vmcnt(0)" ::: "memory");
  __syncthreads();
  int cur = 0;

  for (int jt = jt0; jt <= jtTop; ++jt) {
    // ---- issue next tile's staging early (hides under compute) ----
    if (jt < jtTop) STAGE(cur ^ 1, (jt + 1) * 64);
    char* Ksb = lds + cur * 32768;
    char* Vsb = lds + cur * 32768 + 16384;

    // full-masked wave skip on boundary tiles
    bool active = (jt == jtTop) ? (w >= 4)
                : ((qt >= 8 && jt == jt0) ? (w < 4) : true);
    if (active) {
      // ---- S = Q K^T (16 q-rows x 64 keys per wave) ----
      f32x4 s[4] = {};
      __builtin_amdgcn_s_setprio(1);
#pragma unroll
      for (int nf = 0; nf < 4; ++nf) {
        int row = nf * 16 + fr;
        int sw = fr & 7;
#pragma unroll
        for (int kb = 0; kb < 4; ++kb) {
          half8 bfv = *(const half8*)(Ksb + row * 256 + ((((kb << 2) | fq) ^ sw) << 4));
          s[nf] = __builtin_amdgcn_mfma_f32_16x16x32_f16(qf[kb], bfv, s[nf], 0, 0, 0);
        }
      }
      __builtin_amdgcn_s_setprio(0);
      // ---- masking ----
      int il = (w << 4) + (fq << 2);
      if (jt >= (qt << 1)) {            // causal tiles (last two)
        int dc = (jt << 6) - i0;
#pragma unroll
        for (int nf = 0; nf < 4; ++nf) {
          int jo = nf * 16 + fr + dc;
#pragma unroll
          for (int r = 0; r < 4; ++r)
            if (jo > il + r) s[nf][r] = -3e38f;
        }
      } else if (qt >= 8 && jt - jt0 < 2) {  // window-edge tiles (first two)
        int dl = (jt - jt0) << 6;
#pragma unroll
        for (int nf = 0; nf < 4; ++nf) {
          int jo = nf * 16 + fr + dl;
#pragma unroll
          for (int r = 0; r < 4; ++r)
            if (jo < il + r) s[nf][r] = -3e38f;
        }
      }
      // ---- online softmax (exp2 domain), defer-max rescale ----
      float tm[4];
#pragma unroll
      for (int r = 0; r < 4; ++r)
        tm[r] = fmaxf(fmaxf(s[0][r], s[1][r]), fmaxf(s[2][r], s[3][r]));
#pragma unroll
      for (int r = 0; r < 4; ++r) {
        tm[r] = fmaxf(tm[r], __shfl_xor(tm[r], 1));
        tm[r] = fmaxf(tm[r], __shfl_xor(tm[r], 2));
        tm[r] = fmaxf(tm[r], __shfl_xor(tm[r], 4));
        tm[r] = fmaxf(tm[r], __shfl_xor(tm[r], 8));
      }
      bool need = false;
#pragma unroll
      for (int r = 0; r < 4; ++r) need = need || (tm[r] > mrow[r] + 8.0f);
      if (__any(need)) {
#pragma unroll
        for (int r = 0; r < 4; ++r) {
          float mn = fmaxf(mrow[r], tm[r]);
          float sc = exp2f(mrow[r] - mn);
          mrow[r] = mn;
          lrow[r] *= sc;
#pragma unroll
          for (int of = 0; of < 8; ++of) o[of][r] *= sc;
        }
      }
      float ls[4] = {0.f, 0.f, 0.f, 0.f};
#pragma unroll
      for (int nf = 0; nf < 4; ++nf)
#pragma unroll
        for (int r = 0; r < 4; ++r) {
          float pv = exp2f(s[nf][r] - mrow[r]);
          s[nf][r] = pv;
          ls[r] += pv;
        }
#pragma unroll
      for (int r = 0; r < 4; ++r) {
        float t2 = ls[r];
        t2 += __shfl_xor(t2, 1); t2 += __shfl_xor(t2, 2);
        t2 += __shfl_xor(t2, 4); t2 += __shfl_xor(t2, 8);
        lrow[r] += t2;
      }
      // ---- P -> per-wave LDS (swizzled), wave-local ordering only ----
#pragma unroll
      for (int nf = 0; nf < 4; ++nf) {
        int sbase = (nf << 1) + (fr >> 3);
        int boff = (fr & 7) << 1;
#pragma unroll
        for (int r = 0; r < 4; ++r) {
          int q = (fq << 2) + r;
          *(f16*)(Psb + q * 128 + ((sbase ^ (q & 7)) << 4) + boff) = (f16)s[nf][r];
        }
      }
      asm volatile("s_waitcnt lgkmcnt(0)" ::: "memory");
      __builtin_amdgcn_sched_barrier(0);
      half8 pf0 = *(const half8*)(Psb + fr * 128 + (((fq) ^ (fr & 7)) << 4));
      half8 pf1 = *(const half8*)(Psb + fr * 128 + (((4 | fq) ^ (fr & 7)) << 4));
      // ---- O += P V ----
      __builtin_amdgcn_s_setprio(1);
#pragma unroll
      for (int of = 0; of < 8; ++of) {
        int vrow0 = of * 16 + fr;
        int sw = fr & 7;
        half8 v0 = *(const half8*)(Vsb + vrow0 * 128 + ((fq ^ sw) << 4));
        half8 v1 = *(const half8*)(Vsb + vrow0 * 128 + (((4 | fq) ^ sw) << 4));
        o[of] = __builtin_amdgcn_mfma_f32_16x16x32_f16(pf0, v0, o[of], 0, 0, 0);
        o[of] = __builtin_amdgcn_mfma_f32_16x16x32_f16(pf1, v1, o[of], 0, 0, 0);
      }
      __builtin_amdgcn_s_setprio(0);
    }
    // staged next tile resident + all reads of cur done
    asm volatile("s_waitcnt vmcnt(0)" ::: "memory");
    __syncthreads();
    cur ^= 1;
  }
  // ---- epilogue: normalize + silu(g), write (B,T,H,D) ----
  const f16* gb = gA + ((size_t)(b * T_SEQ) + iw) * NALLP + COL_G + h * DH;
  float* ob = out + ((size_t)(b * T_SEQ) + iw) * DM + h * DH;
#pragma unroll
  for (int r = 0; r < 4; ++r) {
    float inv = 1.0f / lrow[r];
    int ir = fq * 4 + r;
#pragma unroll
    for (int of = 0; of < 8; ++of) {
      int d = of * 16 + fr;
      float gv = (float)gb[(size_t)ir * NALLP + d];
      float sig = gv / (1.0f + expf(-gv));
      ob[(size_t)ir * DM + d] = o[of][r] * inv * sig;
    }
  }
}

extern "C" void kernel_launch(void* const* d_in, const int* in_sizes, int n_in,
                              void* d_out, int out_size, void* d_ws, size_t ws_size,
                              hipStream_t stream) {
  const float* x     = (const float*)d_in[0];
  const float* Wqkv  = (const float*)d_in[1];
  const float* Wrk   = (const float*)d_in[2];
  const float* brk   = (const float*)d_in[3];
  const float* sscal = (const float*)d_in[4];
  const float* Wg    = (const float*)d_in[5];
  float* out = (float*)d_out;
  char* ws = (char*)d_ws;
  size_t off = 0;
  auto alloc = [&](size_t bytes) -> void* {
    void* p = ws + off;
    off += (bytes + 255) & ~(size_t)255;
    return p;
  };
  f16* x16     = (f16*)alloc((size_t)M_ROWS * DM * 2);
  f16* BtAll   = (f16*)alloc((size_t)NALLP * DM * 2);
  f16* CAll    = (f16*)alloc((size_t)M_ROWS * NALLP * 2);
  f16* q16     = (f16*)alloc((size_t)B_SZ * NH * T_SEQ * DH * 2);
  f16* k16     = (f16*)alloc((size_t)B_SZ * NKV * T_SEQ * DH * 2);
  f16* v16     = (f16*)alloc((size_t)B_SZ * NKV * T_SEQ * DH * 2);
  f16* vt16    = (f16*)alloc((size_t)B_SZ * NKV * T_SEQ * DH * 2);

  k_cvt<<<(M_ROWS * DM / 4 + 255) / 256, 256, 0, stream>>>(x, x16, M_ROWS * DM);
  k_cvt_t<<<dim3(DM / 32, NQKV / 32), 256, 0, stream>>>(Wqkv, BtAll, DM, NQKV);
  k_cvt_t<<<dim3(DM / 32, 64 / 32), 256, 0, stream>>>(Wrk, BtAll + (size_t)COL_RK * DM, DM, 64);
  k_cvt_t<<<dim3(DM / 32, DM / 32), 256, 0, stream>>>(Wg, BtAll + (size_t)COL_G * DM, DM, DM);

  k_gemm8<<<dim3(NALLP / 128, M_ROWS / 256), 512, 0, stream>>>(x16, BtAll, CAll);

  k_postproc<<<M_ROWS, 256, 0, stream>>>(CAll, brk, sscal, q16, k16, v16);
  k_vt<<<dim3(T_SEQ / 32, DH / 32, B_SZ * NKV), 256, 0, stream>>>(v16, vt16);

  k_attn<<<dim3(T_SEQ / 128, NH, B_SZ), 512, 0, stream>>>(q16, k16, vt16, CAll, out);
}

// Round 7
// 338.654 us; speedup vs baseline: 1.4721x; 1.0289x over previous
//
#include <hip/hip_runtime.h>

typedef _Float16 f16;
typedef _Float16 half8 __attribute__((ext_vector_type(8)));
typedef _Float16 half4_t __attribute__((ext_vector_type(4)));
typedef float f32x4 __attribute__((ext_vector_type(4)));

#define T_SEQ 2048
#define B_SZ 2
#define DM 2048
#define NH 16
#define NKV 4
#define DH 128
#define NQKV 2560    // (16+4)*128
#define NALL 4736    // 2560 (qkv) + 128 (rk pad) + 2048 (gate)
#define NALLP 4864   // padded to 19*256 for the 256-row GEMM grid
#define COL_RK 2560
#define COL_G 2688
#define M_ROWS 4096  // B*T
#define WIN 1024

typedef __attribute__((address_space(1))) const unsigned int guint;
typedef __attribute__((address_space(3))) unsigned int luint;
__device__ __forceinline__ void gload16(const void* g, void* l) {
  __builtin_amdgcn_global_load_lds((guint*)g, (luint*)l, 16, 0, 0);
}

// ---------------- fp32 -> f16 elementwise ----------------
__global__ void k_cvt(const float* __restrict__ in, f16* __restrict__ out, int n) {
  int i = (blockIdx.x * 256 + threadIdx.x) * 4;
  if (i >= n) return;
  float4 v = *(const float4*)(in + i);
  half4_t o;
  o[0] = (f16)v.x; o[1] = (f16)v.y; o[2] = (f16)v.z; o[3] = (f16)v.w;
  *(half4_t*)(out + i) = o;
}

// ---------------- fp32 (K,N) -> f16 (N,K) transpose-convert ----------------
__global__ __launch_bounds__(256) void k_cvt_t(const float* __restrict__ W,
                                               f16* __restrict__ Wt, int K, int N) {
  __shared__ float tile[32][33];
  int k0 = blockIdx.x * 32, n0 = blockIdx.y * 32;
  int tx = threadIdx.x & 31, ty = threadIdx.x >> 5; // 32 x 8
#pragma unroll
  for (int r = 0; r < 32; r += 8)
    tile[ty + r][tx] = W[(size_t)(k0 + ty + r) * N + n0 + tx];
  __syncthreads();
#pragma unroll
  for (int r = 0; r < 32; r += 8)
    Wt[(size_t)(n0 + ty + r) * K + k0 + tx] = (f16)tile[tx][ty + r];
}

// ---------------- f16 [T][128] -> f16 [128][T] per matrix ----------------
__global__ __launch_bounds__(256) void k_vt(const f16* __restrict__ v, f16* __restrict__ vt) {
  __shared__ f16 tile[32][34];
  int t0 = blockIdx.x * 32, d0 = blockIdx.y * 32, m = blockIdx.z;
  int tx = threadIdx.x & 31, ty = threadIdx.x >> 5;
  const f16* src = v + (size_t)m * T_SEQ * DH;
  f16* dst = vt + (size_t)m * T_SEQ * DH;
#pragma unroll
  for (int r = 0; r < 32; r += 8)
    tile[ty + r][tx] = src[(size_t)(t0 + ty + r) * DH + d0 + tx];
  __syncthreads();
#pragma unroll
  for (int r = 0; r < 32; r += 8)
    dst[(size_t)(d0 + ty + r) * T_SEQ + t0 + tx] = tile[tx][ty + r];
}

// ======== pipelined GEMM: C[M,NALLP](f16) = A[M,K] * Bt[NALLP,K]^T ========
// BM=256, BN=128, BK=32 (one phase per K-step), 8 waves (4M x 2N), wave tile 64x64.
// TRIPLE-buffered LDS (72KB -> 2 blocks/CU for cross-block stall coverage):
//   A[3][256 rows][64B] at 0..49151, B[3][128 rows][64B] at 49152..73727.
// Stage distance 2: phase kt issues tile kt+2's 3 loads; vmcnt(3) at phase end
// leaves only those pending => tile kt+1 provably resident before end barrier.
// Bank swizzle: 16B-slot ^= (row>>1)&3 on gload SOURCE + ds_read addr (dest linear).
#define GEMM_PHASE3(cb, sb, nt)                                                             \
  {                                                                                         \
    char* Ab = lds + (cb) * 16384;                                                          \
    char* Bb = lds + 49152 + (cb) * 8192;                                                   \
    int koff = (nt) * 32;                                                                   \
    half8 af[4], bf[4];                                                                     \
    _Pragma("unroll")                                                                       \
    for (int i = 0; i < 4; ++i)                                                             \
      af[i] = *(const half8*)(Ab + (wm * 64 + i * 16 + fr) * 64 + xsl);                     \
    _Pragma("unroll")                                                                       \
    for (int j = 0; j < 4; ++j)                                                             \
      bf[j] = *(const half8*)(Bb + (wn * 64 + j * 16 + fr) * 64 + xsl);                     \
    gload16(Ag0 + koff, lds + (sb) * 16384 + w * 1024);                                     \
    gload16(Ag1 + koff, lds + (sb) * 16384 + 8192 + w * 1024);                              \
    gload16(Bg + koff, lds + 49152 + (sb) * 8192 + w * 1024);                               \
    __builtin_amdgcn_s_barrier();                                                           \
    __builtin_amdgcn_sched_barrier(0);                                                      \
    asm volatile("s_waitcnt lgkmcnt(0)" ::: "memory");                                      \
    __builtin_amdgcn_sched_barrier(0);                                                      \
    __builtin_amdgcn_s_setprio(1);                                                          \
    _Pragma("unroll")                                                                       \
    for (int i = 0; i < 4; ++i)                                                             \
      _Pragma("unroll")                                                                     \
      for (int j = 0; j < 4; ++j)                                                           \
        acc[i][j] = __builtin_amdgcn_mfma_f32_16x16x32_f16(af[i], bf[j], acc[i][j], 0, 0, 0); \
    __builtin_amdgcn_s_setprio(0);                                                          \
    asm volatile("s_waitcnt vmcnt(3)" ::: "memory");                                        \
    __builtin_amdgcn_s_barrier();                                                           \
    __builtin_amdgcn_sched_barrier(0);                                                      \
  }

__global__ __launch_bounds__(512, 4) void k_gemm8(const f16* __restrict__ A,
                                                  const f16* __restrict__ Bt,
                                                  f16* __restrict__ C) {
  __shared__ __align__(16) char lds[73728];
  const int K = DM;
  // bijective XCD swizzle: nwg = 38*16 = 608 = 8*76
  unsigned orig = blockIdx.y * 38u + blockIdx.x;
  unsigned swz = (orig & 7u) * 76u + (orig >> 3);
  int m0 = (int)(swz / 38u) * 256;
  int n0 = (int)(swz % 38u) * 128;
  int tid = threadIdx.x, lane = tid & 63, w = tid >> 6;
  int wm = w >> 1, wn = w & 1;
  int fr = lane & 15, fq = lane >> 4;
  int xsl = (fq ^ ((fr >> 1) & 3)) << 4;       // read-side swizzled 16B slot
  int sr = tid >> 2, ss = tid & 3;             // staging: row-in-chunk, LDS slot
  int scol = (ss ^ ((sr >> 1) & 3)) * 8;       // inverse-swizzled source col (f16)
  f32x4 acc[4][4] = {};
  const f16* Ag0 = A + (size_t)(m0 + sr) * K + scol;        // rows 0..127 of A-tile
  const f16* Ag1 = A + (size_t)(m0 + 128 + sr) * K + scol;  // rows 128..255
  const f16* Bg  = Bt + (size_t)(n0 + sr) * K + scol;       // rows 0..127 of B-tile

  // prologue: stage tiles 0 and 1 (6 loads); vmcnt(3) -> tile 0 resident
  gload16(Ag0, lds + w * 1024);
  gload16(Ag1, lds + 8192 + w * 1024);
  gload16(Bg, lds + 49152 + w * 1024);
  gload16(Ag0 + 32, lds + 16384 + w * 1024);
  gload16(Ag1 + 32, lds + 16384 + 8192 + w * 1024);
  gload16(Bg + 32, lds + 49152 + 8192 + w * 1024);
  asm volatile("s_waitcnt vmcnt(3)" ::: "memory");
  __builtin_amdgcn_s_barrier();
  __builtin_amdgcn_sched_barrier(0);

  // 64 K-phases: kt = 3*t3 + {0,1,2}, buffers cycle 0,1,2; final phase kt=63.
#pragma unroll 1
  for (int t3 = 0; t3 < 21; ++t3) {
    int ktb = t3 * 3;
    int n1_ = ktb + 3 <= 63 ? ktb + 3 : 63;
    int n2_ = ktb + 4 <= 63 ? ktb + 4 : 63;
    GEMM_PHASE3(0, 2, ktb + 2);
    GEMM_PHASE3(1, 0, n1_);
    GEMM_PHASE3(2, 1, n2_);
  }
  GEMM_PHASE3(0, 2, 63);  // kt=63 (redundant re-stage of tile 63: benign)

#pragma unroll
  for (int i = 0; i < 4; ++i) {
    int row = m0 + wm * 64 + i * 16 + fq * 4;
#pragma unroll
    for (int j = 0; j < 4; ++j) {
      int col = n0 + wn * 64 + j * 16 + fr;
      f16* Cp = C + (size_t)row * NALLP + col;
#pragma unroll
      for (int rr = 0; rr < 4; ++rr) Cp[(size_t)rr * NALLP] = (f16)acc[i][j][rr];
    }
  }
}

// ---------------- RMSNorm + RoPE + scale + pack q/k/v as f16 ----------------
__global__ __launch_bounds__(256) void k_postproc(
    const f16* __restrict__ CA,
    const float* __restrict__ brk, const float* __restrict__ sscal,
    f16* __restrict__ q16, f16* __restrict__ k16, f16* __restrict__ v16) {
  int row = blockIdx.x;              // b*T + t
  int b = row >> 11, t = row & 2047;
  int lane = threadIdx.x & 63, wid = threadIdx.x >> 6;
  int ridx = lane & 31;
  float inv_freq = powf(10000.0f, -(float)(2 * ridx) / 64.0f);
  float fr = (float)t * inv_freq;
  float cs = cosf(fr), sn = sinf(fr);
  float logpos = logf(fminf((float)(t + 1), 1024.0f));
  // 1/sqrt(128) * log2(e): attention works in exp2 domain
  const float rsqrt_d_log2e = 0.08838834764831845f * 1.4426950408889634f;
  const f16* Crow = CA + (size_t)row * NALLP;
#pragma unroll
  for (int p = 0; p < 5; ++p) {
    int h = p * 4 + wid; // 0..19
    float v0 = (float)Crow[h * 128 + lane];
    float v1 = (float)Crow[h * 128 + 64 + lane];
    float ss = v0 * v0 + v1 * v1;
#pragma unroll
    for (int m = 1; m < 64; m <<= 1) ss += __shfl_xor(ss, m);
    float rms = rsqrtf(ss * (1.0f / 128.0f) + 1e-6f);
    v0 *= rms; v1 *= rms;
    if (h < NH) {
      float part = __shfl_xor(v1, 32);
      float vr = (lane < 32) ? (v1 * cs + part * sn) : (v1 * cs - part * sn);
      float scale = sscal[h] * logpos * rsqrt_d_log2e;
      size_t qb = ((size_t)(b * NH + h) * T_SEQ + t) * DH;
      q16[qb + lane]      = (f16)(v0 * scale);
      q16[qb + 64 + lane] = (f16)(vr * scale);
    } else {
      int hk = h - NH;
      size_t kb = ((size_t)(b * NKV + hk) * T_SEQ + t) * DH;
      k16[kb + lane]      = (f16)v0;  // tied kv
      v16[kb + lane]      = (f16)v0;  // tied kv
      v16[kb + 64 + lane] = (f16)v1;  // v
    }
  }
  if (wid == 0) {
    float kr = (float)Crow[COL_RK + lane] + brk[lane];
    float part = __shfl_xor(kr, 32);
    float vr = (lane < 32) ? (kr * cs + part * sn) : (kr * cs - part * sn);
    f16 hv = (f16)vr;
#pragma unroll
    for (int hk = 0; hk < NKV; ++hk)
      k16[((size_t)(b * NKV + hk) * T_SEQ + t) * DH + 64 + lane] = hv;
  }
}

// ---------------- sliding-window flash attention + silu(g) epilogue ----------------
// BQ=128 (8 waves x 16 q-rows), KV tile 64, DOUBLE-BUFFERED K/V staging:
// STAGE(next) issued before compute(cur); one vmcnt(0)+barrier per tile.
// LDS 80KB: Kbuf[c]=c*32768 ([64][128] swz rows), Vbuf[c]=+16384 ([128][64] swz),
// P at 65536 (per-wave 2KB). 80KB -> exactly 2 blocks/CU (matches grid 512/256CU).
// NOTE: launch_bounds min-waves MUST stay low — (512,6) capped VGPRs at 40 and
// spilled the o[] accumulator to scratch (440MB fetch, 2.3x slowdown, round 3).
__global__ __launch_bounds__(512, 2) void k_attn(
    const f16* __restrict__ q16, const f16* __restrict__ k16, const f16* __restrict__ vt16,
    const f16* __restrict__ gA, float* __restrict__ out) {
  __shared__ __align__(16) char lds[81920];
  int bx = blockIdx.x;
  int qt = (bx & 1) ? (15 - (bx >> 1)) : (bx >> 1);  // load-balance heavy/light tiles
  int h = blockIdx.y, b = blockIdx.z, hk = h >> 2;
  int tid = threadIdx.x, lane = tid & 63, w = tid >> 6;
  int i0 = qt * 128, iw = i0 + w * 16;
  int fr = lane & 15, fq = lane >> 4;

  char* Psb = lds + 65536 + w * 2048;

  const f16* qbase = q16 + ((size_t)(b * NH + h) * T_SEQ + iw + fr) * DH;
  half8 qf[4];
#pragma unroll
  for (int kb = 0; kb < 4; ++kb) qf[kb] = *(const half8*)&qbase[kb * 32 + fq * 8];

  f32x4 o[8] = {};
  float mrow[4] = {-1e30f, -1e30f, -1e30f, -1e30f};
  float lrow[4] = {0.f, 0.f, 0.f, 0.f};

  const f16* kg = k16 + (size_t)(b * NKV + hk) * T_SEQ * DH;   // [T][128]
  const f16* vg = vt16 + (size_t)(b * NKV + hk) * T_SEQ * DH;  // [128][T]

  int jtTop = qt * 2 + 1;
  int jt0 = qt >= 8 ? qt * 2 - 16 : 0;

  // staging lane coords (inverse-swizzled source, linear LDS dest)
  int kr_ = tid >> 4, kc_ = ((tid & 15) ^ (kr_ & 7)) * 8;
  int vr_ = tid >> 3, vc_ = ((tid & 7) ^ (vr_ & 7)) * 8;

  auto STAGE = [&](int cbuf, int j0) {
    char* Kb = lds + cbuf * 32768;
    char* Vb = lds + cbuf * 32768 + 16384;
#pragma unroll
    for (int i = 0; i < 2; ++i)
      gload16(kg + (size_t)(j0 + i * 32 + kr_) * DH + kc_, Kb + i * 8192 + w * 1024);
#pragma unroll
    for (int i = 0; i < 2; ++i)
      gload16(vg + (size_t)(i * 64 + vr_) * T_SEQ + j0 + vc_, Vb + i * 8192 + w * 1024);
  };

  // prologue: stage first tile
  STAGE(0, jt0 * 64);
  asm volatile("s_waitcnt vmcnt(0)" ::: "memory");
  __syncthreads();
  int cur = 0;

  for (int jt = jt0; jt <= jtTop; ++jt) {
    // ---- issue next tile's staging early (hides under compute) ----
    if (jt < jtTop) STAGE(cur ^ 1, (jt + 1) * 64);
    char* Ksb = lds + cur * 32768;
    char* Vsb = lds + cur * 32768 + 16384;

    // full-masked wave skip on boundary tiles
    bool active = (jt == jtTop) ? (w >= 4)
                : ((qt >= 8 && jt == jt0) ? (w < 4) : true);
    if (active) {
      // ---- S = Q K^T (16 q-rows x 64 keys per wave) ----
      f32x4 s[4] = {};
      __builtin_amdgcn_s_setprio(1);
#pragma unroll
      for (int nf = 0; nf < 4; ++nf) {
        int row = nf * 16 + fr;
        int sw = fr & 7;
#pragma unroll
        for (int kb = 0; kb < 4; ++kb) {
          half8 bfv = *(const half8*)(Ksb + row * 256 + ((((kb << 2) | fq) ^ sw) << 4));
          s[nf] = __builtin_amdgcn_mfma_f32_16x16x32_f16(qf[kb], bfv, s[nf], 0, 0, 0);
        }
      }
      __builtin_amdgcn_s_setprio(0);
      // ---- masking ----
      int il = (w << 4) + (fq << 2);
      if (jt >= (qt << 1)) {            // causal tiles (last two)
        int dc = (jt << 6) - i0;
#pragma unroll
        for (int nf = 0; nf < 4; ++nf) {
          int jo = nf * 16 + fr + dc;
#pragma unroll
          for (int r = 0; r < 4; ++r)
            if (jo > il + r) s[nf][r] = -3e38f;
        }
      } else if (qt >= 8 && jt - jt0 < 2) {  // window-edge tiles (first two)
        int dl = (jt - jt0) << 6;
#pragma unroll
        for (int nf = 0; nf < 4; ++nf) {
          int jo = nf * 16 + fr + dl;
#pragma unroll
          for (int r = 0; r < 4; ++r)
            if (jo < il + r) s[nf][r] = -3e38f;
        }
      }
      // ---- online softmax (exp2 domain), defer-max rescale ----
      float tm[4];
#pragma unroll
      for (int r = 0; r < 4; ++r)
        tm[r] = fmaxf(fmaxf(s[0][r], s[1][r]), fmaxf(s[2][r], s[3][r]));
#pragma unroll
      for (int r = 0; r < 4; ++r) {
        tm[r] = fmaxf(tm[r], __shfl_xor(tm[r], 1));
        tm[r] = fmaxf(tm[r], __shfl_xor(tm[r], 2));
        tm[r] = fmaxf(tm[r], __shfl_xor(tm[r], 4));
        tm[r] = fmaxf(tm[r], __shfl_xor(tm[r], 8));
      }
      bool need = false;
#pragma unroll
      for (int r = 0; r < 4; ++r) need = need || (tm[r] > mrow[r] + 8.0f);
      if (__any(need)) {
#pragma unroll
        for (int r = 0; r < 4; ++r) {
          float mn = fmaxf(mrow[r], tm[r]);
          float sc = exp2f(mrow[r] - mn);
          mrow[r] = mn;
          lrow[r] *= sc;
#pragma unroll
          for (int of = 0; of < 8; ++of) o[of][r] *= sc;
        }
      }
      float ls[4] = {0.f, 0.f, 0.f, 0.f};
#pragma unroll
      for (int nf = 0; nf < 4; ++nf)
#pragma unroll
        for (int r = 0; r < 4; ++r) {
          float pv = exp2f(s[nf][r] - mrow[r]);
          s[nf][r] = pv;
          ls[r] += pv;
        }
#pragma unroll
      for (int r = 0; r < 4; ++r) {
        float t2 = ls[r];
        t2 += __shfl_xor(t2, 1); t2 += __shfl_xor(t2, 2);
        t2 += __shfl_xor(t2, 4); t2 += __shfl_xor(t2, 8);
        lrow[r] += t2;
      }
      // ---- P -> per-wave LDS (swizzled), wave-local ordering only ----
#pragma unroll
      for (int nf = 0; nf < 4; ++nf) {
        int sbase = (nf << 1) + (fr >> 3);
        int boff = (fr & 7) << 1;
#pragma unroll
        for (int r = 0; r < 4; ++r) {
          int q = (fq << 2) + r;
          *(f16*)(Psb + q * 128 + ((sbase ^ (q & 7)) << 4) + boff) = (f16)s[nf][r];
        }
      }
      asm volatile("s_waitcnt lgkmcnt(0)" ::: "memory");
      __builtin_amdgcn_sched_barrier(0);
      half8 pf0 = *(const half8*)(Psb + fr * 128 + (((fq) ^ (fr & 7)) << 4));
      half8 pf1 = *(const half8*)(Psb + fr * 128 + (((4 | fq) ^ (fr & 7)) << 4));
      // ---- O += P V ----
      __builtin_amdgcn_s_setprio(1);
#pragma unroll
      for (int of = 0; of < 8; ++of) {
        int vrow0 = of * 16 + fr;
        int sw = fr & 7;
        half8 v0 = *(const half8*)(Vsb + vrow0 * 128 + ((fq ^ sw) << 4));
        half8 v1 = *(const half8*)(Vsb + vrow0 * 128 + (((4 | fq) ^ sw) << 4));
        o[of] = __builtin_amdgcn_mfma_f32_16x16x32_f16(pf0, v0, o[of], 0, 0, 0);
        o[of] = __builtin_amdgcn_mfma_f32_16x16x32_f16(pf1, v1, o[of], 0, 0, 0);
      }
      __builtin_amdgcn_s_setprio(0);
    }
    // staged next tile resident + all reads of cur done
    asm volatile("s_waitcnt vmcnt(0)" ::: "memory");
    __syncthreads();
    cur ^= 1;
  }
  // ---- epilogue: normalize + silu(g), write (B,T,H,D) ----
  const f16* gb = gA + ((size_t)(b * T_SEQ) + iw) * NALLP + COL_G + h * DH;
  float* ob = out + ((size_t)(b * T_SEQ) + iw) * DM + h * DH;
#pragma unroll
  for (int r = 0; r < 4; ++r) {
    float inv = 1.0f / lrow[r];
    int ir = fq * 4 + r;
#pragma unroll
    for (int of = 0; of < 8; ++of) {
      int d = of * 16 + fr;
      float gv = (float)gb[(size_t)ir * NALLP + d];
      float sig = gv / (1.0f + expf(-gv));
      ob[(size_t)ir * DM + d] = o[of][r] * inv * sig;
    }
  }
}

extern "C" void kernel_launch(void* const* d_in, const int* in_sizes, int n_in,
                              void* d_out, int out_size, void* d_ws, size_t ws_size,
                              hipStream_t stream) {
  const float* x     = (const float*)d_in[0];
  const float* Wqkv  = (const float*)d_in[1];
  const float* Wrk   = (const float*)d_in[2];
  const float* brk   = (const float*)d_in[3];
  const float* sscal = (const float*)d_in[4];
  const float* Wg    = (const float*)d_in[5];
  float* out = (float*)d_out;
  char* ws = (char*)d_ws;
  size_t off = 0;
  auto alloc = [&](size_t bytes) -> void* {
    void* p = ws + off;
    off += (bytes + 255) & ~(size_t)255;
    return p;
  };
  f16* x16     = (f16*)alloc((size_t)M_ROWS * DM * 2);
  f16* BtAll   = (f16*)alloc((size_t)NALLP * DM * 2);
  f16* CAll    = (f16*)alloc((size_t)M_ROWS * NALLP * 2);
  f16* q16     = (f16*)alloc((size_t)B_SZ * NH * T_SEQ * DH * 2);
  f16* k16     = (f16*)alloc((size_t)B_SZ * NKV * T_SEQ * DH * 2);
  f16* v16     = (f16*)alloc((size_t)B_SZ * NKV * T_SEQ * DH * 2);
  f16* vt16    = (f16*)alloc((size_t)B_SZ * NKV * T_SEQ * DH * 2);

  k_cvt<<<(M_ROWS * DM / 4 + 255) / 256, 256, 0, stream>>>(x, x16, M_ROWS * DM);
  k_cvt_t<<<dim3(DM / 32, NQKV / 32), 256, 0, stream>>>(Wqkv, BtAll, DM, NQKV);
  k_cvt_t<<<dim3(DM / 32, 64 / 32), 256, 0, stream>>>(Wrk, BtAll + (size_t)COL_RK * DM, DM, 64);
  k_cvt_t<<<dim3(DM / 32, DM / 32), 256, 0, stream>>>(Wg, BtAll + (size_t)COL_G * DM, DM, DM);

  k_gemm8<<<dim3(NALLP / 128, M_ROWS / 256), 512, 0, stream>>>(x16, BtAll, CAll);

  k_postproc<<<M_ROWS, 256, 0, stream>>>(CAll, brk, sscal, q16, k16, v16);
  k_vt<<<dim3(T_SEQ / 32, DH / 32, B_SZ * NKV), 256, 0, stream>>>(v16, vt16);

  k_attn<<<dim3(T_SEQ / 128, NH, B_SZ), 512, 0, stream>>>(q16, k16, vt16, CAll, out);
}